// Round 1
// baseline (3508.808 us; speedup 1.0000x reference)
//
#include <hip/hip_runtime.h>
#include <hip/hip_bf16.h>
#include <math.h>

// Problem constants
#define Bc 16
#define Sc 512
#define Dc 768
#define Hc 8
#define DKc 96
#define MAXRELc 128

// ---------------- Generic f32 tiled GEMM ----------------
// C[M,N] = act((A[M,K] @ B[K,N] + bias) / denom[row])
// Supports batching via blockIdx.z with per-batch element strides.
#define BM 64
#define BN 64
#define BKt 16

__global__ __launch_bounds__(256) void gemm_f32(
    const float* __restrict__ A, const float* __restrict__ Bm, float* __restrict__ C,
    int M, int N, int K, int lda, int ldb, int ldc,
    long long sA, long long sB, long long sC,
    const float* __restrict__ bias, const float* __restrict__ denom, int relu_flag)
{
    const int bz = blockIdx.z;
    A  += (long long)bz * sA;
    Bm += (long long)bz * sB;
    C  += (long long)bz * sC;
    const int row0 = blockIdx.y * BM;
    const int col0 = blockIdx.x * BN;

    __shared__ float Ast[BKt][BM + 4];  // transposed A tile, padded (bank-conflict-free, 16B aligned rows)
    __shared__ float Bs[BKt][BN];

    const int tid = threadIdx.x;
    const int tx = tid & 15;
    const int ty = tid >> 4;

    float acc[4][4];
#pragma unroll
    for (int i = 0; i < 4; ++i)
#pragma unroll
        for (int j = 0; j < 4; ++j) acc[i][j] = 0.f;

    for (int k0 = 0; k0 < K; k0 += BKt) {
        // Load A tile 64x16 -> transposed LDS
        {
            const int r = tid >> 2;          // 0..63
            const int c = (tid & 3) * 4;     // 0,4,8,12
            const float4 a4 = *(const float4*)(A + (long long)(row0 + r) * lda + k0 + c);
            Ast[c + 0][r] = a4.x;
            Ast[c + 1][r] = a4.y;
            Ast[c + 2][r] = a4.z;
            Ast[c + 3][r] = a4.w;
        }
        // Load B tile 16x64
        {
            const int r = tid >> 4;          // 0..15
            const int c = (tid & 15) * 4;    // 0..60
            *(float4*)(&Bs[r][c]) = *(const float4*)(Bm + (long long)(k0 + r) * ldb + col0 + c);
        }
        __syncthreads();

#pragma unroll
        for (int kk = 0; kk < BKt; ++kk) {
            const float4 av = *(const float4*)(&Ast[kk][ty * 4]);
            const float4 bv = *(const float4*)(&Bs[kk][tx * 4]);
            const float a0 = av.x, a1 = av.y, a2 = av.z, a3 = av.w;
            const float b0 = bv.x, b1 = bv.y, b2 = bv.z, b3 = bv.w;
            acc[0][0] += a0 * b0; acc[0][1] += a0 * b1; acc[0][2] += a0 * b2; acc[0][3] += a0 * b3;
            acc[1][0] += a1 * b0; acc[1][1] += a1 * b1; acc[1][2] += a1 * b2; acc[1][3] += a1 * b3;
            acc[2][0] += a2 * b0; acc[2][1] += a2 * b1; acc[2][2] += a2 * b2; acc[2][3] += a2 * b3;
            acc[3][0] += a3 * b0; acc[3][1] += a3 * b1; acc[3][2] += a3 * b2; acc[3][3] += a3 * b3;
        }
        __syncthreads();
    }

    const int r0 = row0 + ty * 4;
    const int c0 = col0 + tx * 4;
#pragma unroll
    for (int i = 0; i < 4; ++i) {
        const long long gr = r0 + i;
        float inv = 1.f;
        if (denom) inv = 1.f / denom[(long long)bz * M + gr];
        float4 v4;
        float v[4];
#pragma unroll
        for (int j = 0; j < 4; ++j) {
            float v1 = acc[i][j];
            if (bias) v1 += bias[c0 + j];
            v1 *= inv;
            if (relu_flag) v1 = fmaxf(v1, 0.f);
            v[j] = v1;
        }
        v4.x = v[0]; v4.y = v[1]; v4.z = v[2]; v4.w = v[3];
        *(float4*)(C + gr * ldc + c0) = v4;
    }
}

// ---------------- Fused adjacency kernel ----------------
// Per block: one batch b, 8 query rows. Computes per-head scores (QK^T*scale + rel
// bias, key-masked), per-row softmax, head-mean -> adj row; forces diag=1, row
// masks, writes adj to d_out slice and denom (= rowsum + 1) to ws.
__global__ __launch_bounds__(256) void adj_kernel(
    const float* __restrict__ Q, const float* __restrict__ Kp,
    const int* __restrict__ tok, const float* __restrict__ rel_emb,
    float* __restrict__ adj_out, float* __restrict__ denom_out)
{
    const int b  = blockIdx.x >> 6;          // 512/8 = 64 tiles per batch
    const int i0 = (blockIdx.x & 63) * 8;
    const int tid = threadIdx.x;
    const float scale = 0.10206207261596577f; // 1/sqrt(96)

    __shared__ float qh[8][DKc];      // current head's Q rows
    __shared__ float qm[8][DKc];      // head-mean Q rows
    __shared__ float rels[8][Sc];     // rel bias * scale
    __shared__ float sc[8][Sc];       // current head scores
    __shared__ float adjacc[8][Sc];   // accumulated softmax mean

    // head-mean of Q for these 8 rows
    for (int idx = tid; idx < 8 * DKc; idx += 256) {
        const int ii = idx / DKc, kk = idx % DKc;
        const float* qrow = Q + (long long)(b * Sc + i0 + ii) * Dc + kk;
        float s = 0.f;
#pragma unroll
        for (int h = 0; h < Hc; ++h) s += qrow[h * DKc];
        qm[ii][kk] = s * 0.125f;
    }
    // zero adj accumulator
    for (int idx = tid; idx < 8 * Sc; idx += 256) {
        ((float*)adjacc)[idx] = 0.f;
    }
    __syncthreads();

    // relative-position bias (shared by all heads): rels[ii][j] = scale * dot(qm[ii], rel_emb[dist])
    for (int idx = tid; idx < 8 * Sc; idx += 256) {
        const int ii = idx >> 9;  // /512
        const int j  = idx & 511;
        int dist = j - (i0 + ii);
        dist = dist < -MAXRELc ? -MAXRELc : (dist > MAXRELc ? MAXRELc : dist);
        const float4* rr = (const float4*)(rel_emb + (long long)(dist + MAXRELc) * DKc);
        float a = 0.f;
#pragma unroll
        for (int k4 = 0; k4 < DKc / 4; ++k4) {
            const float4 rv = rr[k4];
            const float4 qv = *(const float4*)(&qm[ii][k4 * 4]);
            a += rv.x * qv.x + rv.y * qv.y + rv.z * qv.z + rv.w * qv.w;
        }
        rels[ii][j] = a * scale;
    }
    __syncthreads();

    const int row = tid >> 5;   // 0..7
    const int g   = tid & 31;   // 0..31

    for (int h = 0; h < Hc; ++h) {
        // stage this head's Q rows
        for (int idx = tid; idx < 8 * DKc; idx += 256) {
            const int ii = idx / DKc, kk = idx % DKc;
            qh[ii][kk] = Q[(long long)(b * Sc + i0 + ii) * Dc + h * DKc + kk];
        }
        __syncthreads();

        // scores: each thread handles 2 key columns
#pragma unroll
        for (int jj = 0; jj < 2; ++jj) {
            const int j = tid + jj * 256;
            const bool masked = (tok[b * Sc + j] == 0);
            const float4* kr = (const float4*)(Kp + (long long)(b * Sc + j) * Dc + h * DKc);
            float acc[8];
#pragma unroll
            for (int ii = 0; ii < 8; ++ii) acc[ii] = 0.f;
#pragma unroll
            for (int k4 = 0; k4 < DKc / 4; ++k4) {
                const float4 kv = kr[k4];
#pragma unroll
                for (int ii = 0; ii < 8; ++ii) {
                    const float4 qv = *(const float4*)(&qh[ii][k4 * 4]);
                    acc[ii] += kv.x * qv.x + kv.y * qv.y + kv.z * qv.z + kv.w * qv.w;
                }
            }
#pragma unroll
            for (int ii = 0; ii < 8; ++ii) {
                sc[ii][j] = masked ? -1e9f : (acc[ii] * scale + rels[ii][j]);
            }
        }
        __syncthreads();

        // per-row softmax (32 lanes per row), accumulate mean into adjacc
        float mx = -INFINITY;
#pragma unroll
        for (int m = 0; m < 16; ++m) mx = fmaxf(mx, sc[row][g + 32 * m]);
#pragma unroll
        for (int off = 16; off; off >>= 1) mx = fmaxf(mx, __shfl_xor(mx, off));
        float sum = 0.f;
#pragma unroll
        for (int m = 0; m < 16; ++m) sum += __expf(sc[row][g + 32 * m] - mx);
#pragma unroll
        for (int off = 16; off; off >>= 1) sum += __shfl_xor(sum, off);
        const float inv = 0.125f / sum;
#pragma unroll
        for (int m = 0; m < 16; ++m) {
            const int j = g + 32 * m;
            adjacc[row][j] += __expf(sc[row][j] - mx) * inv;
        }
        __syncthreads();
    }

    // postprocess: diag=1, row mask, write adj + denom
    const int i = i0 + row;
    const bool rowmask = (tok[b * Sc + i] != 0);
    float rsum = 0.f;
#pragma unroll
    for (int m = 0; m < 16; ++m) {
        const int j = g + 32 * m;
        float v = adjacc[row][j];
        v = (j == i) ? 1.0f : v;
        if (!rowmask) v = 0.f;
        adj_out[((long long)(b * Sc + i)) * Sc + j] = v;
        rsum += v;
    }
#pragma unroll
    for (int off = 16; off; off >>= 1) rsum += __shfl_xor(rsum, off);
    if (g == 0) denom_out[b * Sc + i] = rsum + 1.0f;
}

// ---------------- small fused kernels ----------------
__global__ void comb_kernel(const float* __restrict__ o1, const float* __restrict__ o2,
                            const float* __restrict__ scale_w, float* __restrict__ outp)
{
    const long long idx = (long long)blockIdx.x * 256 + threadIdx.x;
    const float s0 = scale_w[0], s1 = scale_w[1];
    const float m = fmaxf(s0, s1);
    const float e0 = __expf(s0 - m), e1 = __expf(s1 - m);
    const float w0 = e0 / (e0 + e1), w1 = e1 / (e0 + e1);
    outp[idx] = w0 * o1[idx] + w1 * o2[idx];
}

__global__ void pool_kernel(const float* __restrict__ x, float* __restrict__ gavg, float* __restrict__ gmax)
{
    const int b = blockIdx.x;
    const int c = blockIdx.y * 256 + threadIdx.x;
    float s = 0.f, mval = -INFINITY;
    for (int ss = 0; ss < Sc; ++ss) {
        const float v = x[((long long)(b * Sc + ss)) * Dc + c];
        s += v;
        mval = fmaxf(mval, v);
    }
    gavg[b * Dc + c] = s * (1.f / Sc);
    gmax[b * Dc + c] = mval;
}

// out[b][n] = act(bias[n] + sum_k in1[b][k]*W[k][n] (+ sum_k in2[b][k]*W[K1+k][n]))
__global__ void smallmm_kernel(const float* __restrict__ in1, const float* __restrict__ in2,
                               const float* __restrict__ W, const float* __restrict__ bias,
                               float* __restrict__ outp, int K1, int do_sigmoid)
{
    const int idx = blockIdx.x * 256 + threadIdx.x;  // 16*768
    const int n = idx % Dc;
    const int b = idx / Dc;
    float acc = bias[n];
    const float* w = W + n;
    for (int k = 0; k < K1; ++k) acc += in1[b * K1 + k] * w[(long long)k * Dc];
    if (in2) {
        for (int k = 0; k < K1; ++k) acc += in2[b * K1 + k] * w[(long long)(K1 + k) * Dc];
    }
    if (do_sigmoid) acc = 1.f / (1.f + __expf(-acc));
    outp[idx] = acc;
}

__global__ void final_kernel(const float* __restrict__ x, const float* __restrict__ gate,
                             const float* __restrict__ gc, float* __restrict__ outp)
{
    const long long idx = (long long)blockIdx.x * 256 + threadIdx.x;
    const int c = (int)(idx % Dc);
    const long long bs = idx / Dc;
    const int b = (int)(bs / Sc);
    outp[idx] = x[idx] + gate[b * Dc + c] * gc[b * Dc + c];
}

// ---------------- launch ----------------
extern "C" void kernel_launch(void* const* d_in, const int* in_sizes, int n_in,
                              void* d_out, int out_size, void* d_ws, size_t ws_size,
                              hipStream_t stream)
{
    (void)in_sizes; (void)n_in; (void)out_size; (void)ws_size;

    const float* X       = (const float*)d_in[0];
    const int*   tok     = (const int*)d_in[1];
    const float* Wq      = (const float*)d_in[3];
    const float* bq      = (const float*)d_in[4];
    const float* Wk      = (const float*)d_in[5];
    const float* bk      = (const float*)d_in[6];
    const float* rel_emb = (const float*)d_in[7];
    const float* W0      = (const float*)d_in[8];
    const float* b0      = (const float*)d_in[9];
    const float* W1      = (const float*)d_in[10];
    const float* b1      = (const float*)d_in[11];
    const float* scale_w = (const float*)d_in[12];
    const float* Wf      = (const float*)d_in[13];
    const float* bf      = (const float*)d_in[14];
    const float* Wfc     = (const float*)d_in[15];
    const float* bfc     = (const float*)d_in[16];
    const float* Wg      = (const float*)d_in[17];
    const float* bg      = (const float*)d_in[18];

    float* outp = (float*)d_out;
    const long long NBSD = (long long)Bc * Sc * Dc;   // 6291456
    float* adj = outp + NBSD;

    float* ws   = (float*)d_ws;
    float* Qb   = ws;                    // Q proj; later out2
    float* Kb   = ws + NBSD;             // K proj; later ax / ax2 / combined
    float* Ab   = ws + 2 * NBSD;         // out1; later x
    float* denom = ws + 3 * NBSD;        // 8192
    float* gavg = denom + Bc * Sc;       // 12288
    float* gmax = gavg + Bc * Dc;
    float* gcb  = gmax + Bc * Dc;
    float* gate = gcb + Bc * Dc;

    const int MS = Bc * Sc;  // 8192

    auto gemm = [&](const float* A, const float* Bmat, float* C, int M, int N, int K,
                    int lda, int ldb, int ldc, long long sA, long long sB, long long sC,
                    int batch, const float* bias, const float* den, int relu) {
        dim3 grid(N / BN, M / BM, batch);
        gemm_f32<<<grid, 256, 0, stream>>>(A, Bmat, C, M, N, K, lda, ldb, ldc, sA, sB, sC, bias, den, relu);
    };

    // 1-2: Q/K projections
    gemm(X, Wq, Qb, MS, Dc, Dc, Dc, Dc, Dc, 0, 0, 0, 1, bq, nullptr, 0);
    gemm(X, Wk, Kb, MS, Dc, Dc, Dc, Dc, Dc, 0, 0, 0, 1, bk, nullptr, 0);

    // 3: fused adjacency (adj into d_out slice, denom into ws)
    adj_kernel<<<Bc * (Sc / 8), 256, 0, stream>>>(Qb, Kb, tok, rel_emb, adj, denom);

    // 4: ax = adj @ X   (batched)  -> Kb
    gemm(adj, X, Kb, Sc, Dc, Sc, Sc, Dc, Dc, (long long)Sc * Sc, (long long)Sc * Dc, (long long)Sc * Dc,
         Bc, nullptr, nullptr, 0);
    // 5: out1 = relu((ax @ W0 + b0)/denom) -> Ab
    gemm(Kb, W0, Ab, MS, Dc, Dc, Dc, Dc, Dc, 0, 0, 0, 1, b0, denom, 1);
    // 6: ax2 = adj @ out1 (batched) -> Kb
    gemm(adj, Ab, Kb, Sc, Dc, Sc, Sc, Dc, Dc, (long long)Sc * Sc, (long long)Sc * Dc, (long long)Sc * Dc,
         Bc, nullptr, nullptr, 0);
    // 7: out2 = relu((ax2 @ W1 + b1)/denom) -> Qb
    gemm(Kb, W1, Qb, MS, Dc, Dc, Dc, Dc, Dc, 0, 0, 0, 1, b1, denom, 1);

    // 8: combined = w0*out1 + w1*out2 -> Kb
    comb_kernel<<<(int)(NBSD / 256), 256, 0, stream>>>(Ab, Qb, scale_w, Kb);
    // 9: x = combined @ Wf + bf -> Ab
    gemm(Kb, Wf, Ab, MS, Dc, Dc, Dc, Dc, Dc, 0, 0, 0, 1, bf, nullptr, 0);

    // 10: pooling
    pool_kernel<<<dim3(Bc, Dc / 256), 256, 0, stream>>>(Ab, gavg, gmax);
    // 11: gc = [gavg,gmax] @ Wfc + bfc
    smallmm_kernel<<<(Bc * Dc) / 256, 256, 0, stream>>>(gavg, gmax, Wfc, bfc, gcb, Dc, 0);
    // 12: gate = sigmoid(gc @ Wg + bg)
    smallmm_kernel<<<(Bc * Dc) / 256, 256, 0, stream>>>(gcb, nullptr, Wg, bg, gate, Dc, 1);
    // 13: outputs = x + gate*gc
    final_kernel<<<(int)(NBSD / 256), 256, 0, stream>>>(Ab, gate, gcb, outp);
}

// Round 2
// 2005.730 us; speedup vs baseline: 1.7494x; 1.7494x over previous
//
#include <hip/hip_runtime.h>
#include <hip/hip_bf16.h>
#include <math.h>

// Problem constants
#define Bc 16
#define Sc 512
#define Dc 768
#define Hc 8
#define DKc 96
#define MAXRELc 128

typedef __attribute__((ext_vector_type(8))) short bf16x8;
typedef __attribute__((ext_vector_type(4))) float f32x4;

static __device__ __forceinline__ unsigned short f2b(float f) {
    __hip_bfloat16 h = __float2bfloat16(f);
    return *(unsigned short*)&h;
}
static __device__ __forceinline__ float b2f(unsigned short u) {
    union { float f; unsigned v; } x;
    x.v = ((unsigned)u) << 16;
    return x.f;
}

// ---------------- Generic f32 tiled GEMM ----------------
// C[M,N] = act((A[M,K] @ B[K,N] + bias) / denom[row]); optional bf16 side output.
#define BM 64
#define BN 64
#define BKt 16

__global__ __launch_bounds__(256) void gemm_f32(
    const float* __restrict__ A, const float* __restrict__ Bm, float* __restrict__ C,
    int M, int N, int K, int lda, int ldb, int ldc,
    long long sA, long long sB, long long sC,
    const float* __restrict__ bias, const float* __restrict__ denom, int relu_flag,
    unsigned short* __restrict__ bf_out, float bf_scale)
{
    const int bz = blockIdx.z;
    A  += (long long)bz * sA;
    Bm += (long long)bz * sB;
    if (C) C += (long long)bz * sC;
    const int row0 = blockIdx.y * BM;
    const int col0 = blockIdx.x * BN;

    __shared__ float Ast[BKt][BM + 4];
    __shared__ float Bs[BKt][BN];

    const int tid = threadIdx.x;
    const int tx = tid & 15;
    const int ty = tid >> 4;

    float acc[4][4];
#pragma unroll
    for (int i = 0; i < 4; ++i)
#pragma unroll
        for (int j = 0; j < 4; ++j) acc[i][j] = 0.f;

    for (int k0 = 0; k0 < K; k0 += BKt) {
        {
            const int r = tid >> 2;
            const int c = (tid & 3) * 4;
            const float4 a4 = *(const float4*)(A + (long long)(row0 + r) * lda + k0 + c);
            Ast[c + 0][r] = a4.x;
            Ast[c + 1][r] = a4.y;
            Ast[c + 2][r] = a4.z;
            Ast[c + 3][r] = a4.w;
        }
        {
            const int r = tid >> 4;
            const int c = (tid & 15) * 4;
            *(float4*)(&Bs[r][c]) = *(const float4*)(Bm + (long long)(k0 + r) * ldb + col0 + c);
        }
        __syncthreads();

#pragma unroll
        for (int kk = 0; kk < BKt; ++kk) {
            const float4 av = *(const float4*)(&Ast[kk][ty * 4]);
            const float4 bv = *(const float4*)(&Bs[kk][tx * 4]);
            const float a0 = av.x, a1 = av.y, a2 = av.z, a3 = av.w;
            const float b0 = bv.x, b1 = bv.y, b2 = bv.z, b3 = bv.w;
            acc[0][0] += a0 * b0; acc[0][1] += a0 * b1; acc[0][2] += a0 * b2; acc[0][3] += a0 * b3;
            acc[1][0] += a1 * b0; acc[1][1] += a1 * b1; acc[1][2] += a1 * b2; acc[1][3] += a1 * b3;
            acc[2][0] += a2 * b0; acc[2][1] += a2 * b1; acc[2][2] += a2 * b2; acc[2][3] += a2 * b3;
            acc[3][0] += a3 * b0; acc[3][1] += a3 * b1; acc[3][2] += a3 * b2; acc[3][3] += a3 * b3;
        }
        __syncthreads();
    }

    const int r0 = row0 + ty * 4;
    const int c0 = col0 + tx * 4;
#pragma unroll
    for (int i = 0; i < 4; ++i) {
        const long long gr = r0 + i;
        float inv = 1.f;
        if (denom) inv = 1.f / denom[(long long)bz * M + gr];
        float v[4];
#pragma unroll
        for (int j = 0; j < 4; ++j) {
            float v1 = acc[i][j];
            if (bias) v1 += bias[c0 + j];
            v1 *= inv;
            if (relu_flag) v1 = fmaxf(v1, 0.f);
            v[j] = v1;
        }
        if (bf_out) {
            ushort4 o;
            o.x = f2b(v[0] * bf_scale);
            o.y = f2b(v[1] * bf_scale);
            o.z = f2b(v[2] * bf_scale);
            o.w = f2b(v[3] * bf_scale);
            *(ushort4*)(bf_out + gr * ldc + c0) = o;
        }
        if (C) {
            float4 v4;
            v4.x = v[0]; v4.y = v[1]; v4.z = v[2]; v4.w = v[3];
            *(float4*)(C + gr * ldc + c0) = v4;
        }
    }
}

// ---------------- q_mean @ rel_emb^T table ----------------
// rb[b,i,n] = dot(mean_h Qbf[b,i,h,:], rel_emb[n,:])  (scale already folded in Qbf)
__global__ __launch_bounds__(256) void qmean_rb_kernel(
    const unsigned short* __restrict__ Qbf, const float* __restrict__ rel_emb,
    float* __restrict__ rb)
{
    const int bi = blockIdx.x;            // b*Sc + i
    const int t = threadIdx.x;
    __shared__ float qm[DKc];

    if (t < DKc) {
        const unsigned short* qr = Qbf + (long long)bi * Dc + t;
        float s = 0.f;
#pragma unroll
        for (int h = 0; h < Hc; ++h) s += b2f(qr[h * DKc]);
        qm[t] = s * 0.125f;
    }
    __syncthreads();

    for (int n = t; n < 2 * MAXRELc + 1; n += 256) {
        const float4* rr = (const float4*)(rel_emb + (long long)n * DKc);
        float acc = 0.f;
#pragma unroll
        for (int k4 = 0; k4 < DKc / 4; ++k4) {
            const float4 rv = rr[k4];
            const float4 qv = *(const float4*)(&qm[k4 * 4]);
            acc += rv.x * qv.x + rv.y * qv.y + rv.z * qv.z + rv.w * qv.w;
        }
        rb[(long long)bi * (2 * MAXRELc + 1) + n] = acc;
    }
}

// ---------------- Fused adjacency via MFMA ----------------
// Block = 4 waves, one batch b, 16 query rows; wave w owns cols [w*128, w*128+128).
// Per head: scores via mfma_f32_16x16x32_bf16 with fragments loaded straight from
// global bf16 Q/K (A: lane=row l&15, k=(l>>4)*8+i; B: lane=col l&15, same k).
// Bias (rel + key-mask) pre-gathered in regs; softmax without max-subtraction
// (scores O(1), masked = -1e9 -> exp 0). adj mean accumulated in regs.
__global__ __launch_bounds__(256) void adj_mfma_kernel(
    const unsigned short* __restrict__ Qbf, const unsigned short* __restrict__ Kbf,
    const int* __restrict__ tok, const float* __restrict__ rb,
    float* __restrict__ adj_out, float* __restrict__ denom_out)
{
    const int b  = blockIdx.x >> 5;          // 32 row-tiles per batch
    const int i0 = (blockIdx.x & 31) << 4;
    const int tid = threadIdx.x;
    const int w  = tid >> 6;
    const int l  = tid & 63;
    const int lg = l >> 4;
    const int ll = l & 15;
    const int c0 = w << 7;

    __shared__ float red[4][16];

    const int tokbase = b * Sc;

    float bias[8][4];
    float adjacc[8][4];
#pragma unroll
    for (int f = 0; f < 8; ++f) {
        const int j = c0 + f * 16 + ll;
        const bool km = (tok[tokbase + j] == 0);
#pragma unroll
        for (int r = 0; r < 4; ++r) {
            const int i = i0 + lg * 4 + r;
            int dd = j - i;
            dd = dd < -MAXRELc ? -MAXRELc : (dd > MAXRELc ? MAXRELc : dd);
            bias[f][r] = km ? -1e9f
                            : rb[(long long)(tokbase + i) * (2 * MAXRELc + 1) + dd + MAXRELc];
            adjacc[f][r] = 0.f;
        }
    }

    const long long qrow = (long long)(tokbase + i0 + ll) * Dc;

    for (int h = 0; h < Hc; ++h) {
        const int hoff = h * DKc;
        bf16x8 afr[3];
#pragma unroll
        for (int ks = 0; ks < 3; ++ks)
            afr[ks] = *(const bf16x8*)(Qbf + qrow + hoff + ks * 32 + lg * 8);

        float ex[8][4];
        float psum[4] = {0.f, 0.f, 0.f, 0.f};
#pragma unroll
        for (int f = 0; f < 8; ++f) {
            const long long krow = (long long)(tokbase + c0 + f * 16 + ll) * Dc + hoff;
            f32x4 acc = {0.f, 0.f, 0.f, 0.f};
#pragma unroll
            for (int ks = 0; ks < 3; ++ks) {
                const bf16x8 bfr = *(const bf16x8*)(Kbf + krow + ks * 32 + lg * 8);
                acc = __builtin_amdgcn_mfma_f32_16x16x32_bf16(afr[ks], bfr, acc, 0, 0, 0);
            }
#pragma unroll
            for (int r = 0; r < 4; ++r) {
                const float e = __expf(acc[r] + bias[f][r]);
                ex[f][r] = e;
                psum[r] += e;
            }
        }
#pragma unroll
        for (int r = 0; r < 4; ++r) {
            psum[r] += __shfl_xor(psum[r], 1);
            psum[r] += __shfl_xor(psum[r], 2);
            psum[r] += __shfl_xor(psum[r], 4);
            psum[r] += __shfl_xor(psum[r], 8);
        }
        if (ll == 0) {
#pragma unroll
            for (int r = 0; r < 4; ++r) red[w][lg * 4 + r] = psum[r];
        }
        __syncthreads();
#pragma unroll
        for (int r = 0; r < 4; ++r) {
            const int rr = lg * 4 + r;
            const float s = red[0][rr] + red[1][rr] + red[2][rr] + red[3][rr];
            const float inv = 0.125f / s;
#pragma unroll
            for (int f = 0; f < 8; ++f) adjacc[f][r] += ex[f][r] * inv;
        }
        __syncthreads();
    }

    // epilogue: diag=1, row mask, write adj + denom(rowsum+1)
    bool rowm[4];
#pragma unroll
    for (int r = 0; r < 4; ++r) rowm[r] = (tok[tokbase + i0 + lg * 4 + r] != 0);

    float psum[4] = {0.f, 0.f, 0.f, 0.f};
#pragma unroll
    for (int f = 0; f < 8; ++f) {
        const int j = c0 + f * 16 + ll;
#pragma unroll
        for (int r = 0; r < 4; ++r) {
            const int i = i0 + lg * 4 + r;
            float v = adjacc[f][r];
            if (j == i) v = 1.f;
            if (!rowm[r]) v = 0.f;
            adj_out[(long long)(tokbase + i) * Sc + j] = v;
            psum[r] += v;
        }
    }
#pragma unroll
    for (int r = 0; r < 4; ++r) {
        psum[r] += __shfl_xor(psum[r], 1);
        psum[r] += __shfl_xor(psum[r], 2);
        psum[r] += __shfl_xor(psum[r], 4);
        psum[r] += __shfl_xor(psum[r], 8);
    }
    if (ll == 0) {
#pragma unroll
        for (int r = 0; r < 4; ++r) red[w][lg * 4 + r] = psum[r];
    }
    __syncthreads();
    if (w == 0 && ll == 0) {
#pragma unroll
        for (int r = 0; r < 4; ++r) {
            const int rr = lg * 4 + r;
            denom_out[tokbase + i0 + rr] =
                red[0][rr] + red[1][rr] + red[2][rr] + red[3][rr] + 1.f;
        }
    }
}

// ---------------- small fused kernels ----------------
__global__ void comb_kernel(const float* __restrict__ o1, const float* __restrict__ o2,
                            const float* __restrict__ scale_w, float* __restrict__ outp)
{
    const long long idx = (long long)blockIdx.x * 256 + threadIdx.x;
    const float s0 = scale_w[0], s1 = scale_w[1];
    const float m = fmaxf(s0, s1);
    const float e0 = __expf(s0 - m), e1 = __expf(s1 - m);
    const float w0 = e0 / (e0 + e1), w1 = e1 / (e0 + e1);
    outp[idx] = w0 * o1[idx] + w1 * o2[idx];
}

__global__ void pool_kernel(const float* __restrict__ x, float* __restrict__ gavg, float* __restrict__ gmax)
{
    const int b = blockIdx.x;
    const int c = blockIdx.y * 256 + threadIdx.x;
    float s = 0.f, mval = -INFINITY;
    for (int ss = 0; ss < Sc; ++ss) {
        const float v = x[((long long)(b * Sc + ss)) * Dc + c];
        s += v;
        mval = fmaxf(mval, v);
    }
    gavg[b * Dc + c] = s * (1.f / Sc);
    gmax[b * Dc + c] = mval;
}

__global__ void smallmm_kernel(const float* __restrict__ in1, const float* __restrict__ in2,
                               const float* __restrict__ W, const float* __restrict__ bias,
                               float* __restrict__ outp, int K1, int do_sigmoid)
{
    const int idx = blockIdx.x * 256 + threadIdx.x;
    const int n = idx % Dc;
    const int b = idx / Dc;
    float acc = bias[n];
    const float* w = W + n;
    for (int k = 0; k < K1; ++k) acc += in1[b * K1 + k] * w[(long long)k * Dc];
    if (in2) {
        for (int k = 0; k < K1; ++k) acc += in2[b * K1 + k] * w[(long long)(K1 + k) * Dc];
    }
    if (do_sigmoid) acc = 1.f / (1.f + __expf(-acc));
    outp[idx] = acc;
}

__global__ void final_kernel(const float* __restrict__ x, const float* __restrict__ gate,
                             const float* __restrict__ gc, float* __restrict__ outp)
{
    const long long idx = (long long)blockIdx.x * 256 + threadIdx.x;
    const int c = (int)(idx % Dc);
    const long long bs = idx / Dc;
    const int b = (int)(bs / Sc);
    outp[idx] = x[idx] + gate[b * Dc + c] * gc[b * Dc + c];
}

// ---------------- launch ----------------
extern "C" void kernel_launch(void* const* d_in, const int* in_sizes, int n_in,
                              void* d_out, int out_size, void* d_ws, size_t ws_size,
                              hipStream_t stream)
{
    (void)in_sizes; (void)n_in; (void)out_size; (void)ws_size;

    const float* X       = (const float*)d_in[0];
    const int*   tok     = (const int*)d_in[1];
    const float* Wq      = (const float*)d_in[3];
    const float* bq      = (const float*)d_in[4];
    const float* Wk      = (const float*)d_in[5];
    const float* bk      = (const float*)d_in[6];
    const float* rel_emb = (const float*)d_in[7];
    const float* W0      = (const float*)d_in[8];
    const float* b0      = (const float*)d_in[9];
    const float* W1      = (const float*)d_in[10];
    const float* b1      = (const float*)d_in[11];
    const float* scale_w = (const float*)d_in[12];
    const float* Wf      = (const float*)d_in[13];
    const float* bf      = (const float*)d_in[14];
    const float* Wfc     = (const float*)d_in[15];
    const float* bfc     = (const float*)d_in[16];
    const float* Wg      = (const float*)d_in[17];
    const float* bg      = (const float*)d_in[18];

    float* outp = (float*)d_out;
    const long long NBSD = (long long)Bc * Sc * Dc;   // 6291456
    float* adj = outp + NBSD;

    float* ws = (float*)d_ws;
    // Big f32 buffers (phase 2)
    float* Af = ws;                       // ax / ax2 / combined
    float* Bf = ws + NBSD;                // out1 / x
    float* Cf = ws + 2 * NBSD;            // out2
    float* denom = ws + 3 * NBSD;
    float* gavg = denom + Bc * Sc;
    float* gmax = gavg + Bc * Dc;
    float* gcb  = gmax + Bc * Dc;
    float* gate = gcb + Bc * Dc;

    // Phase-1 overlay (dead before Af/Bf are written): Qbf, Kbf, rb inside Af..Bf
    unsigned short* Qbf = (unsigned short*)ws;                 // NBSD bf16 = NBSD/2 floats
    unsigned short* Kbf = (unsigned short*)(ws + NBSD / 2);    // NBSD bf16
    float* rb = ws + NBSD;                                     // B*S*257 floats (8.4 MB)

    const int MS = Bc * Sc;  // 8192
    const float qscale = 0.10206207261596577f;  // 1/sqrt(96)

    auto gemm = [&](const float* A, const float* Bmat, float* C, int M, int N, int K,
                    int lda, int ldb, int ldc, long long sA, long long sB, long long sC,
                    int batch, const float* bias, const float* den, int relu,
                    unsigned short* bfo, float bscale) {
        dim3 grid(N / BN, M / BM, batch);
        gemm_f32<<<grid, 256, 0, stream>>>(A, Bmat, C, M, N, K, lda, ldb, ldc,
                                           sA, sB, sC, bias, den, relu, bfo, bscale);
    };

    // 1-2: Q/K projections -> bf16 only (scale folded into Q)
    gemm(X, Wq, nullptr, MS, Dc, Dc, Dc, Dc, Dc, 0, 0, 0, 1, bq, nullptr, 0, Qbf, qscale);
    gemm(X, Wk, nullptr, MS, Dc, Dc, Dc, Dc, Dc, 0, 0, 0, 1, bk, nullptr, 0, Kbf, 1.0f);

    // 3a: rel-bias table rb[b,i,n]
    qmean_rb_kernel<<<MS, 256, 0, stream>>>(Qbf, rel_emb, rb);
    // 3b: fused adjacency (adj into d_out slice, denom into ws)
    adj_mfma_kernel<<<Bc * (Sc / 16), 256, 0, stream>>>(Qbf, Kbf, tok, rb, adj, denom);

    // 4: ax = adj @ X -> Af
    gemm(adj, X, Af, Sc, Dc, Sc, Sc, Dc, Dc, (long long)Sc * Sc, (long long)Sc * Dc,
         (long long)Sc * Dc, Bc, nullptr, nullptr, 0, nullptr, 1.f);
    // 5: out1 = relu((ax @ W0 + b0)/denom) -> Bf
    gemm(Af, W0, Bf, MS, Dc, Dc, Dc, Dc, Dc, 0, 0, 0, 1, b0, denom, 1, nullptr, 1.f);
    // 6: ax2 = adj @ out1 -> Af
    gemm(adj, Bf, Af, Sc, Dc, Sc, Sc, Dc, Dc, (long long)Sc * Sc, (long long)Sc * Dc,
         (long long)Sc * Dc, Bc, nullptr, nullptr, 0, nullptr, 1.f);
    // 7: out2 = relu((ax2 @ W1 + b1)/denom) -> Cf
    gemm(Af, W1, Cf, MS, Dc, Dc, Dc, Dc, Dc, 0, 0, 0, 1, b1, denom, 1, nullptr, 1.f);

    // 8: combined = w0*out1 + w1*out2 -> Af
    comb_kernel<<<(int)(NBSD / 256), 256, 0, stream>>>(Bf, Cf, scale_w, Af);
    // 9: x = combined @ Wf + bf -> Bf
    gemm(Af, Wf, Bf, MS, Dc, Dc, Dc, Dc, Dc, 0, 0, 0, 1, bf, nullptr, 0, nullptr, 1.f);

    // 10: pooling
    pool_kernel<<<dim3(Bc, Dc / 256), 256, 0, stream>>>(Bf, gavg, gmax);
    // 11: gc = [gavg,gmax] @ Wfc + bfc
    smallmm_kernel<<<(Bc * Dc) / 256, 256, 0, stream>>>(gavg, gmax, Wfc, bfc, gcb, Dc, 0);
    // 12: gate = sigmoid(gc @ Wg + bg)
    smallmm_kernel<<<(Bc * Dc) / 256, 256, 0, stream>>>(gcb, nullptr, Wg, bg, gate, Dc, 1);
    // 13: outputs = x + gate*gc
    final_kernel<<<(int)(NBSD / 256), 256, 0, stream>>>(Bf, gate, gcb, outp);
}

// Round 4
// 584.644 us; speedup vs baseline: 6.0016x; 3.4307x over previous
//
#include <hip/hip_runtime.h>
#include <hip/hip_bf16.h>
#include <math.h>

// Problem constants
#define Bc 16
#define Sc 512
#define Dc 768
#define Hc 8
#define DKc 96
#define MAXRELc 128

typedef __attribute__((ext_vector_type(8))) short bf16x8;
typedef __attribute__((ext_vector_type(4))) float f32x4;

static __device__ __forceinline__ unsigned short f2b(float f) {
    __hip_bfloat16 h = __float2bfloat16(f);
    return *(unsigned short*)&h;
}
static __device__ __forceinline__ float b2f(unsigned short u) {
    union { float f; unsigned v; } x;
    x.v = ((unsigned)u) << 16;
    return x.f;
}

// ---------------- f32 -> bf16 convert ----------------
__global__ __launch_bounds__(256) void cvt_bf16_kernel(const float* __restrict__ in,
                                                       unsigned short* __restrict__ out)
{
    const long long idx = ((long long)blockIdx.x * 256 + threadIdx.x) * 8;
    const float4 a = *(const float4*)(in + idx);
    const float4 b = *(const float4*)(in + idx + 4);
    bf16x8 v;
    v[0] = (short)f2b(a.x); v[1] = (short)f2b(a.y); v[2] = (short)f2b(a.z); v[3] = (short)f2b(a.w);
    v[4] = (short)f2b(b.x); v[5] = (short)f2b(b.y); v[6] = (short)f2b(b.z); v[7] = (short)f2b(b.w);
    *(bf16x8*)(out + idx) = v;
}

// ---------------- weight transpose+convert: W[K][N] f32 -> Wt[N][K] bf16 ----------------
__global__ __launch_bounds__(256) void wtrans_kernel(const float* __restrict__ W,
                                                     unsigned short* __restrict__ Wt,
                                                     int Kd, int Nd)
{
    __shared__ float td[64][65];
    const int n0 = blockIdx.x * 64, k0 = blockIdx.y * 64;
    const int t = threadIdx.x, r = t >> 2, c4 = (t & 3) * 16;
#pragma unroll
    for (int j = 0; j < 4; ++j) {
        const float4 v = *(const float4*)(W + (long long)(k0 + r) * Nd + n0 + c4 + j * 4);
        td[r][c4 + j * 4 + 0] = v.x;
        td[r][c4 + j * 4 + 1] = v.y;
        td[r][c4 + j * 4 + 2] = v.z;
        td[r][c4 + j * 4 + 3] = v.w;
    }
    __syncthreads();
    bf16x8 v0, v1;
#pragma unroll
    for (int i = 0; i < 8; ++i) {
        v0[i] = (short)f2b(td[c4 + i][r]);
        v1[i] = (short)f2b(td[c4 + 8 + i][r]);
    }
    unsigned short* dst = Wt + (long long)(n0 + r) * Kd + k0 + c4;
    *(bf16x8*)dst = v0;
    *(bf16x8*)(dst + 8) = v1;
}

// ---------------- activation transpose: in[16*512][768] bf16 -> outT[16][768][512] bf16 ----------------
__global__ __launch_bounds__(256) void atrans_kernel(const unsigned short* __restrict__ in,
                                                     unsigned short* __restrict__ outT)
{
    __shared__ unsigned short td[64][66];
    const int b = blockIdx.z, s0 = blockIdx.y * 64, n0 = blockIdx.x * 64;
    const int t = threadIdx.x, r = t >> 2, c = (t & 3) * 16;
    const unsigned short* src = in + ((long long)(b * Sc + s0 + r)) * Dc + n0 + c;
    *(bf16x8*)&td[r][c] = *(const bf16x8*)src;
    *(bf16x8*)&td[r][c + 8] = *(const bf16x8*)(src + 8);
    __syncthreads();
    bf16x8 v0, v1;
#pragma unroll
    for (int i = 0; i < 8; ++i) {
        v0[i] = (short)td[c + i][r];
        v1[i] = (short)td[c + 8 + i][r];
    }
    unsigned short* dst = outT + ((long long)b * Dc + n0 + r) * Sc + s0 + c;
    *(bf16x8*)dst = v0;
    *(bf16x8*)(dst + 8) = v1;
}

// ---------------- bf16 MFMA GEMM (both operands [rows][K] row-major; B = "B^T") ----------------
// C[row][col] = act((sum_k A[row][k]*Bt[col][k] + bias[col]) / denom[row])
// 128x128 tile, BK=32, 4 waves (64x64 quadrant each), reg-staged LDS, 2-barrier loop.
__global__ __launch_bounds__(256) void gemm_bf16(
    const unsigned short* __restrict__ A, const unsigned short* __restrict__ Bt,
    int K, long long sA, long long sB, long long sC,
    const float* __restrict__ bias, const float* __restrict__ denom, int relu_flag,
    float* __restrict__ Cf, unsigned short* __restrict__ Cbf, float bscale)
{
    const int bz = blockIdx.z;
    A  += (long long)bz * sA;
    Bt += (long long)bz * sB;
    const int row0 = blockIdx.y * 128, col0 = blockIdx.x * 128;

    __shared__ unsigned short Al[128 * 32];
    __shared__ unsigned short Bl[128 * 32];

    const int t = threadIdx.x;
    const int w = t >> 6, l = t & 63, lg = l >> 4, ll = l & 15;
    const int wr = (w >> 1) * 64, wc = (w & 1) * 64;

    f32x4 acc[4][4];
#pragma unroll
    for (int m = 0; m < 4; ++m)
#pragma unroll
        for (int n = 0; n < 4; ++n) acc[m][n] = (f32x4){0.f, 0.f, 0.f, 0.f};

    const unsigned short* Ag = A + (long long)(row0 + (t >> 2)) * K + (t & 3) * 8;
    const unsigned short* Bg = Bt + (long long)(col0 + (t >> 2)) * K + (t & 3) * 8;
    const long long half = 64LL * K;

    for (int k0 = 0; k0 < K; k0 += 32) {
        const bf16x8 a0 = *(const bf16x8*)(Ag + k0);
        const bf16x8 a1 = *(const bf16x8*)(Ag + half + k0);
        const bf16x8 b0 = *(const bf16x8*)(Bg + k0);
        const bf16x8 b1 = *(const bf16x8*)(Bg + half + k0);
        __syncthreads();
        *(bf16x8*)&Al[t * 8] = a0;
        *(bf16x8*)&Al[2048 + t * 8] = a1;
        *(bf16x8*)&Bl[t * 8] = b0;
        *(bf16x8*)&Bl[2048 + t * 8] = b1;
        __syncthreads();

        bf16x8 af[4], bv[4];
#pragma unroll
        for (int m = 0; m < 4; ++m)
            af[m] = *(const bf16x8*)&Al[(wr + m * 16 + ll) * 32 + lg * 8];
#pragma unroll
        for (int n = 0; n < 4; ++n)
            bv[n] = *(const bf16x8*)&Bl[(wc + n * 16 + ll) * 32 + lg * 8];
#pragma unroll
        for (int m = 0; m < 4; ++m)
#pragma unroll
            for (int n = 0; n < 4; ++n)
                acc[m][n] = __builtin_amdgcn_mfma_f32_16x16x32_bf16(af[m], bv[n], acc[m][n], 0, 0, 0);
    }

    // epilogue: C/D layout col=ll, row=lg*4+r
#pragma unroll
    for (int m = 0; m < 4; ++m) {
#pragma unroll
        for (int n = 0; n < 4; ++n) {
            const int colg = col0 + wc + n * 16 + ll;
            const float bvl = bias ? bias[colg] : 0.f;
#pragma unroll
            for (int r = 0; r < 4; ++r) {
                const int rowg = row0 + wr + m * 16 + lg * 4 + r;
                float v = acc[m][n][r] + bvl;
                if (denom) v /= denom[rowg];
                if (relu_flag) v = fmaxf(v, 0.f);
                const long long off = (long long)bz * sC + (long long)rowg * Dc + colg;
                if (Cbf) Cbf[off] = f2b(v * bscale);
                if (Cf) Cf[off] = v;
            }
        }
    }
}

// ---------------- q_mean @ rel_emb^T table ----------------
__global__ __launch_bounds__(256) void qmean_rb_kernel(
    const unsigned short* __restrict__ Qbf, const float* __restrict__ rel_emb,
    float* __restrict__ rb)
{
    const int bi = blockIdx.x;
    const int t = threadIdx.x;
    __shared__ float qm[DKc];

    if (t < DKc) {
        const unsigned short* qr = Qbf + (long long)bi * Dc + t;
        float s = 0.f;
#pragma unroll
        for (int h = 0; h < Hc; ++h) s += b2f(qr[h * DKc]);
        qm[t] = s * 0.125f;
    }
    __syncthreads();

    for (int n = t; n < 2 * MAXRELc + 1; n += 256) {
        const float4* rr = (const float4*)(rel_emb + (long long)n * DKc);
        float acc = 0.f;
#pragma unroll
        for (int k4 = 0; k4 < DKc / 4; ++k4) {
            const float4 rv = rr[k4];
            const float4 qv = *(const float4*)(&qm[k4 * 4]);
            acc += rv.x * qv.x + rv.y * qv.y + rv.z * qv.z + rv.w * qv.w;
        }
        rb[(long long)bi * (2 * MAXRELc + 1) + n] = acc;
    }
}

// ---------------- Fused adjacency via MFMA ----------------
__global__ __launch_bounds__(256) void adj_mfma_kernel(
    const unsigned short* __restrict__ Qbf, const unsigned short* __restrict__ Kbf,
    const int* __restrict__ tok, const float* __restrict__ rb,
    float* __restrict__ adj_out, unsigned short* __restrict__ adjbf_out,
    float* __restrict__ denom_out)
{
    const int b  = blockIdx.x >> 5;
    const int i0 = (blockIdx.x & 31) << 4;
    const int tid = threadIdx.x;
    const int w  = tid >> 6;
    const int l  = tid & 63;
    const int lg = l >> 4;
    const int ll = l & 15;
    const int c0 = w << 7;

    __shared__ float red[4][16];

    const int tokbase = b * Sc;

    float bias[8][4];
    float adjacc[8][4];
#pragma unroll
    for (int f = 0; f < 8; ++f) {
        const int j = c0 + f * 16 + ll;
        const bool km = (tok[tokbase + j] == 0);
#pragma unroll
        for (int r = 0; r < 4; ++r) {
            const int i = i0 + lg * 4 + r;
            int dd = j - i;
            dd = dd < -MAXRELc ? -MAXRELc : (dd > MAXRELc ? MAXRELc : dd);
            bias[f][r] = km ? -1e9f
                            : rb[(long long)(tokbase + i) * (2 * MAXRELc + 1) + dd + MAXRELc];
            adjacc[f][r] = 0.f;
        }
    }

    const long long qrow = (long long)(tokbase + i0 + ll) * Dc;

    for (int h = 0; h < Hc; ++h) {
        const int hoff = h * DKc;
        bf16x8 afr[3];
#pragma unroll
        for (int ks = 0; ks < 3; ++ks)
            afr[ks] = *(const bf16x8*)(Qbf + qrow + hoff + ks * 32 + lg * 8);

        float ex[8][4];
        float psum[4] = {0.f, 0.f, 0.f, 0.f};
#pragma unroll
        for (int f = 0; f < 8; ++f) {
            const long long krow = (long long)(tokbase + c0 + f * 16 + ll) * Dc + hoff;
            f32x4 acc = {0.f, 0.f, 0.f, 0.f};
#pragma unroll
            for (int ks = 0; ks < 3; ++ks) {
                const bf16x8 bfr = *(const bf16x8*)(Kbf + krow + ks * 32 + lg * 8);
                acc = __builtin_amdgcn_mfma_f32_16x16x32_bf16(afr[ks], bfr, acc, 0, 0, 0);
            }
#pragma unroll
            for (int r = 0; r < 4; ++r) {
                const float e = __expf(acc[r] + bias[f][r]);
                ex[f][r] = e;
                psum[r] += e;
            }
        }
#pragma unroll
        for (int r = 0; r < 4; ++r) {
            psum[r] += __shfl_xor(psum[r], 1);
            psum[r] += __shfl_xor(psum[r], 2);
            psum[r] += __shfl_xor(psum[r], 4);
            psum[r] += __shfl_xor(psum[r], 8);
        }
        if (ll == 0) {
#pragma unroll
            for (int r = 0; r < 4; ++r) red[w][lg * 4 + r] = psum[r];
        }
        __syncthreads();
#pragma unroll
        for (int r = 0; r < 4; ++r) {
            const int rr = lg * 4 + r;
            const float s = red[0][rr] + red[1][rr] + red[2][rr] + red[3][rr];
            const float inv = 0.125f / s;
#pragma unroll
            for (int f = 0; f < 8; ++f) adjacc[f][r] += ex[f][r] * inv;
        }
        __syncthreads();
    }

    bool rowm[4];
#pragma unroll
    for (int r = 0; r < 4; ++r) rowm[r] = (tok[tokbase + i0 + lg * 4 + r] != 0);

    float psum[4] = {0.f, 0.f, 0.f, 0.f};
#pragma unroll
    for (int f = 0; f < 8; ++f) {
        const int j = c0 + f * 16 + ll;
#pragma unroll
        for (int r = 0; r < 4; ++r) {
            const int i = i0 + lg * 4 + r;
            float v = adjacc[f][r];
            if (j == i) v = 1.f;
            if (!rowm[r]) v = 0.f;
            const long long off = (long long)(tokbase + i) * Sc + j;
            adj_out[off] = v;
            adjbf_out[off] = f2b(v);
            psum[r] += v;
        }
    }
#pragma unroll
    for (int r = 0; r < 4; ++r) {
        psum[r] += __shfl_xor(psum[r], 1);
        psum[r] += __shfl_xor(psum[r], 2);
        psum[r] += __shfl_xor(psum[r], 4);
        psum[r] += __shfl_xor(psum[r], 8);
    }
    if (ll == 0) {
#pragma unroll
        for (int r = 0; r < 4; ++r) red[w][lg * 4 + r] = psum[r];
    }
    __syncthreads();
    if (w == 0 && ll == 0) {
#pragma unroll
        for (int r = 0; r < 4; ++r) {
            const int rr = lg * 4 + r;
            denom_out[tokbase + i0 + rr] =
                red[0][rr] + red[1][rr] + red[2][rr] + red[3][rr] + 1.f;
        }
    }
}

// ---------------- combine (bf16 in/out) ----------------
__global__ __launch_bounds__(256) void comb_bf_kernel(const unsigned short* __restrict__ o1,
                                                      const unsigned short* __restrict__ o2,
                                                      const float* __restrict__ scale_w,
                                                      unsigned short* __restrict__ outp)
{
    const long long idx = ((long long)blockIdx.x * 256 + threadIdx.x) * 8;
    const float s0 = scale_w[0], s1 = scale_w[1];
    const float m = fmaxf(s0, s1);
    const float e0 = __expf(s0 - m), e1 = __expf(s1 - m);
    const float w0 = e0 / (e0 + e1), w1 = e1 / (e0 + e1);
    const bf16x8 a = *(const bf16x8*)(o1 + idx);
    const bf16x8 b = *(const bf16x8*)(o2 + idx);
    bf16x8 o;
#pragma unroll
    for (int i = 0; i < 8; ++i)
        o[i] = (short)f2b(w0 * b2f((unsigned short)a[i]) + w1 * b2f((unsigned short)b[i]));
    *(bf16x8*)(outp + idx) = o;
}

// ---------------- pooling (split + reduce) ----------------
__global__ __launch_bounds__(256) void pool_part_kernel(const float* __restrict__ x,
                                                        float* __restrict__ psum,
                                                        float* __restrict__ pmax)
{
    const int b = blockIdx.z, ct = blockIdx.x, scn = blockIdx.y;
    const int t = threadIdx.x, c = ct * 64 + (t & 63), sg = t >> 6;
    float s = 0.f, m = -INFINITY;
#pragma unroll
    for (int si = 0; si < 16; ++si) {
        const int srow = scn * 64 + sg * 16 + si;
        const float v = x[((long long)(b * Sc + srow)) * Dc + c];
        s += v;
        m = fmaxf(m, v);
    }
    __shared__ float rs[4][64], rm[4][64];
    rs[sg][t & 63] = s;
    rm[sg][t & 63] = m;
    __syncthreads();
    if (t < 64) {
        s = rs[0][t] + rs[1][t] + rs[2][t] + rs[3][t];
        m = fmaxf(fmaxf(rm[0][t], rm[1][t]), fmaxf(rm[2][t], rm[3][t]));
        const long long o = ((long long)b * 8 + scn) * Dc + ct * 64 + t;
        psum[o] = s;
        pmax[o] = m;
    }
}

__global__ __launch_bounds__(256) void pool_red_kernel(const float* __restrict__ psum,
                                                       const float* __restrict__ pmax,
                                                       float* __restrict__ gpool)
{
    const int idx = blockIdx.x * 256 + threadIdx.x;
    const int b = idx / Dc, c = idx % Dc;
    float s = 0.f, m = -INFINITY;
#pragma unroll
    for (int i = 0; i < 8; ++i) {
        const long long o = ((long long)b * 8 + i) * Dc + c;
        s += psum[o];
        m = fmaxf(m, pmax[o]);
    }
    gpool[(long long)b * 1536 + c] = s * (1.f / Sc);
    gpool[(long long)b * 1536 + Dc + c] = m;
}

// ---------------- skinny GEMM: out[16][768] = in[16][K] @ W[K][768] ----------------
__global__ __launch_bounds__(256) void skinny_partial(const float* __restrict__ in,
                                                      const float* __restrict__ W,
                                                      float* __restrict__ part, int K)
{
    __shared__ float sin_[16][96];
    const int t = threadIdx.x;
    const int nt = blockIdx.x, kc = blockIdx.y;
    const int k0 = kc * 96;
    for (int idx = t; idx < 16 * 96; idx += 256) {
        const int b = idx / 96, c = idx % 96;
        sin_[b][c] = in[(long long)b * K + k0 + c];
    }
    __syncthreads();
    const int n = nt * 64 + (t & 63), kg = t >> 6;
    float acc[16];
#pragma unroll
    for (int b = 0; b < 16; ++b) acc[b] = 0.f;
    for (int kk = 0; kk < 24; ++kk) {
        const float wv = W[(long long)(k0 + kg * 24 + kk) * Dc + n];
#pragma unroll
        for (int b = 0; b < 16; ++b) acc[b] += sin_[b][kg * 24 + kk] * wv;
    }
    float* dst = part + ((long long)(kc * 4 + kg) * 16) * Dc + n;
#pragma unroll
    for (int b = 0; b < 16; ++b) dst[(long long)b * Dc] = acc[b];
}

__global__ __launch_bounds__(256) void skinny_reduce(const float* __restrict__ part,
                                                     const float* __restrict__ bias,
                                                     float* __restrict__ outp,
                                                     int nslices, int do_sigmoid)
{
    const int idx = blockIdx.x * 256 + threadIdx.x;
    const int n = idx % Dc;
    float s = bias[n];
    for (int i = 0; i < nslices; ++i) s += part[(long long)i * (16 * Dc) + idx];
    if (do_sigmoid) s = 1.f / (1.f + __expf(-s));
    outp[idx] = s;
}

__global__ __launch_bounds__(256) void final_kernel(const float* __restrict__ x,
                                                    const float* __restrict__ gate,
                                                    const float* __restrict__ gc,
                                                    float* __restrict__ outp)
{
    const long long idx = (long long)blockIdx.x * 256 + threadIdx.x;
    const int c = (int)(idx % Dc);
    const long long bs = idx / Dc;
    const int b = (int)(bs / Sc);
    outp[idx] = x[idx] + gate[b * Dc + c] * gc[b * Dc + c];
}

// ---------------- launch ----------------
extern "C" void kernel_launch(void* const* d_in, const int* in_sizes, int n_in,
                              void* d_out, int out_size, void* d_ws, size_t ws_size,
                              hipStream_t stream)
{
    (void)in_sizes; (void)n_in; (void)out_size; (void)ws_size;

    const float* X       = (const float*)d_in[0];
    const int*   tok     = (const int*)d_in[1];
    const float* Wq      = (const float*)d_in[3];
    const float* bq      = (const float*)d_in[4];
    const float* Wk      = (const float*)d_in[5];
    const float* bk      = (const float*)d_in[6];
    const float* rel_emb = (const float*)d_in[7];
    const float* W0      = (const float*)d_in[8];
    const float* b0      = (const float*)d_in[9];
    const float* W1      = (const float*)d_in[10];
    const float* b1      = (const float*)d_in[11];
    const float* scale_w = (const float*)d_in[12];
    const float* Wf      = (const float*)d_in[13];
    const float* bf      = (const float*)d_in[14];
    const float* Wfc     = (const float*)d_in[15];
    const float* bfc     = (const float*)d_in[16];
    const float* Wg      = (const float*)d_in[17];
    const float* bg      = (const float*)d_in[18];

    float* outp = (float*)d_out;
    const long long NBSD = (long long)Bc * Sc * Dc;   // 6291456
    float* adj = outp + NBSD;

    char* wsb = (char*)d_ws;
    const long long MiB = 1048576LL;
    // R0 [0,12MiB): Xbf -> rb -> out2bf -> final smalls
    unsigned short* Xbf    = (unsigned short*)(wsb);
    float*          rb     = (float*)(wsb);
    unsigned short* out2bf = (unsigned short*)(wsb);
    float* gpool   = (float*)(wsb);
    float* gcb     = (float*)(wsb + 128 * 1024);
    float* gate    = (float*)(wsb + 192 * 1024);
    float* poolsum = (float*)(wsb + 256 * 1024);
    float* poolmax = (float*)(wsb + 640 * 1024);
    float* pp1     = (float*)(wsb + 1 * MiB);   // 3 MiB
    float* pp2     = (float*)(wsb + 4 * MiB);   // 1.5 MiB
    // R1 [12,24): Qbf -> combbf
    unsigned short* Qbf    = (unsigned short*)(wsb + 12 * MiB);
    unsigned short* combbf = Qbf;
    // R2 [24,36): Kbf -> out1bf
    unsigned short* Kbf    = (unsigned short*)(wsb + 24 * MiB);
    unsigned short* out1bf = Kbf;
    // R3 [36,48): Xt -> out1t ; xf32 spans [36,60)
    unsigned short* Xt    = (unsigned short*)(wsb + 36 * MiB);
    unsigned short* out1t = Xt;
    float*          xf    = (float*)(wsb + 36 * MiB);
    // R4 [48,56): adjbf
    unsigned short* adjbf = (unsigned short*)(wsb + 48 * MiB);
    // R5 [56,68): Wqt/Wkt (early) -> axbf/ax2bf
    unsigned short* Wqt  = (unsigned short*)(wsb + 56 * MiB);
    unsigned short* Wkt  = (unsigned short*)(wsb + 56 * MiB + 1179648);
    unsigned short* axbf = (unsigned short*)(wsb + 56 * MiB);
    // WT [68,~71.4): persistent weights + denom
    unsigned short* W0t = (unsigned short*)(wsb + 68 * MiB);
    unsigned short* W1t = (unsigned short*)(wsb + 68 * MiB + 1179648);
    unsigned short* Wft = (unsigned short*)(wsb + 68 * MiB + 2359296);
    float*          denom = (float*)(wsb + 68 * MiB + 3538944);

    const float qscale = 0.10206207261596577f;  // 1/sqrt(96)

    auto gemm = [&](const unsigned short* A, const unsigned short* Bt, int M, int K,
                    long long sA, long long sB, long long sC, int batch,
                    const float* bias, const float* den, int relu,
                    float* Cf, unsigned short* Cbf, float bscale) {
        dim3 grid(Dc / 128, M / 128, batch);
        gemm_bf16<<<grid, 256, 0, stream>>>(A, Bt, K, sA, sB, sC, bias, den, relu, Cf, Cbf, bscale);
    };

    // a: X -> bf16
    cvt_bf16_kernel<<<(int)(NBSD / 2048), 256, 0, stream>>>(X, Xbf);
    // b: weight transposes
    wtrans_kernel<<<dim3(12, 12), 256, 0, stream>>>(Wq, Wqt, Dc, Dc);
    wtrans_kernel<<<dim3(12, 12), 256, 0, stream>>>(Wk, Wkt, Dc, Dc);
    wtrans_kernel<<<dim3(12, 12), 256, 0, stream>>>(W0, W0t, Dc, Dc);
    wtrans_kernel<<<dim3(12, 12), 256, 0, stream>>>(W1, W1t, Dc, Dc);
    wtrans_kernel<<<dim3(12, 12), 256, 0, stream>>>(Wf, Wft, Dc, Dc);
    // c,d: Q/K projections (bf16 out; qscale folded into Q)
    gemm(Xbf, Wqt, Bc * Sc, Dc, 0, 0, 0, 1, bq, nullptr, 0, nullptr, Qbf, qscale);
    gemm(Xbf, Wkt, Bc * Sc, Dc, 0, 0, 0, 1, bk, nullptr, 0, nullptr, Kbf, 1.f);
    // g: Xt (transpose while Xbf still live)
    atrans_kernel<<<dim3(12, 8, 16), 256, 0, stream>>>(Xbf, Xt);
    // e: rel-bias table (rb overlays Xbf region — Xbf dead now)
    qmean_rb_kernel<<<Bc * Sc, 256, 0, stream>>>(Qbf, rel_emb, rb);
    // f: fused adjacency
    adj_mfma_kernel<<<Bc * (Sc / 16), 256, 0, stream>>>(Qbf, Kbf, tok, rb, adj, adjbf, denom);
    // h: ax = adj @ X (batched; B = Xt)
    gemm(adjbf, Xt, Sc, Sc, (long long)Sc * Sc, (long long)Dc * Sc, (long long)Sc * Dc,
         Bc, nullptr, nullptr, 0, nullptr, axbf, 1.f);
    // i: out1 = relu((ax @ W0 + b0)/denom)
    gemm(axbf, W0t, Bc * Sc, Dc, 0, 0, 0, 1, b0, denom, 1, nullptr, out1bf, 1.f);
    // j: out1t
    atrans_kernel<<<dim3(12, 8, 16), 256, 0, stream>>>(out1bf, out1t);
    // k: ax2 = adj @ out1 (batched)
    gemm(adjbf, out1t, Sc, Sc, (long long)Sc * Sc, (long long)Dc * Sc, (long long)Sc * Dc,
         Bc, nullptr, nullptr, 0, nullptr, axbf, 1.f);
    // l: out2 = relu((ax2 @ W1 + b1)/denom)
    gemm(axbf, W1t, Bc * Sc, Dc, 0, 0, 0, 1, b1, denom, 1, nullptr, out2bf, 1.f);
    // m: combined
    comb_bf_kernel<<<(int)(NBSD / 2048), 256, 0, stream>>>(out1bf, out2bf, scale_w, combbf);
    // n: x = combined @ Wf + bf (f32)
    gemm(combbf, Wft, Bc * Sc, Dc, 0, 0, 0, 1, bf, nullptr, 0, xf, nullptr, 1.f);
    // o: pooling
    pool_part_kernel<<<dim3(12, 8, 16), 256, 0, stream>>>(xf, poolsum, poolmax);
    pool_red_kernel<<<(Bc * Dc) / 256, 256, 0, stream>>>(poolsum, poolmax, gpool);
    // p: gc = [gavg|gmax] @ Wfc + bfc
    skinny_partial<<<dim3(12, 16), 256, 0, stream>>>(gpool, Wfc, pp1, 2 * Dc);
    skinny_reduce<<<(Bc * Dc) / 256, 256, 0, stream>>>(pp1, bfc, gcb, 64, 0);
    // q: gate = sigmoid(gc @ Wg + bg)
    skinny_partial<<<dim3(12, 8), 256, 0, stream>>>(gcb, Wg, pp2, Dc);
    skinny_reduce<<<(Bc * Dc) / 256, 256, 0, stream>>>(pp2, bg, gate, 32, 1);
    // r: outputs = x + gate*gc
    final_kernel<<<(int)(NBSD / 256), 256, 0, stream>>>(xf, gate, gcb, outp);
}

// Round 5
// 510.541 us; speedup vs baseline: 6.8727x; 1.1451x over previous
//
#include <hip/hip_runtime.h>
#include <hip/hip_bf16.h>
#include <math.h>

// Problem constants
#define Bc 16
#define Sc 512
#define Dc 768
#define Hc 8
#define DKc 96
#define MAXRELc 128
#define RBLD 384  // padded rel-bias table width

typedef __attribute__((ext_vector_type(8))) short bf16x8;
typedef __attribute__((ext_vector_type(4))) float f32x4;

static __device__ __forceinline__ unsigned short f2b(float f) {
    __hip_bfloat16 h = __float2bfloat16(f);
    return *(unsigned short*)&h;
}
static __device__ __forceinline__ float b2f(unsigned short u) {
    union { float f; unsigned v; } x;
    x.v = ((unsigned)u) << 16;
    return x.f;
}

// ---- async global->LDS (16B/lane), CK-style int-roundtrip addrspace casts ----
#if defined(__has_builtin)
#if __has_builtin(__builtin_amdgcn_global_load_lds)
#define HAS_GLLDS 1
#endif
#endif

#ifdef HAS_GLLDS
typedef __attribute__((address_space(1))) void as1_void;
typedef __attribute__((address_space(3))) void as3_void;
static __device__ __forceinline__ void gl_lds16(const void* g, void* l) {
    __builtin_amdgcn_global_load_lds((as1_void*)(unsigned long long)g,
                                     (as3_void*)(unsigned long long)l, 16, 0, 0);
}
#endif

// ---------------- f32 -> bf16 convert ----------------
__global__ __launch_bounds__(256) void cvt_bf16_kernel(const float* __restrict__ in,
                                                       unsigned short* __restrict__ out)
{
    const long long idx = ((long long)blockIdx.x * 256 + threadIdx.x) * 8;
    const float4 a = *(const float4*)(in + idx);
    const float4 b = *(const float4*)(in + idx + 4);
    bf16x8 v;
    v[0] = (short)f2b(a.x); v[1] = (short)f2b(a.y); v[2] = (short)f2b(a.z); v[3] = (short)f2b(a.w);
    v[4] = (short)f2b(b.x); v[5] = (short)f2b(b.y); v[6] = (short)f2b(b.z); v[7] = (short)f2b(b.w);
    *(bf16x8*)(out + idx) = v;
}

// ---------------- 5 weight transposes in one launch: W[768][768] f32 -> Wt[768][768] bf16 ----------------
struct WT5 { const float* s[5]; unsigned short* d[5]; };

__global__ __launch_bounds__(256) void wtrans5_kernel(WT5 p)
{
    const float* W = p.s[blockIdx.z];
    unsigned short* Wt = p.d[blockIdx.z];
    __shared__ float td[64][65];
    const int n0 = blockIdx.x * 64, k0 = blockIdx.y * 64;
    const int t = threadIdx.x, r = t >> 2, c4 = (t & 3) * 16;
#pragma unroll
    for (int j = 0; j < 4; ++j) {
        const float4 v = *(const float4*)(W + (long long)(k0 + r) * Dc + n0 + c4 + j * 4);
        td[r][c4 + j * 4 + 0] = v.x;
        td[r][c4 + j * 4 + 1] = v.y;
        td[r][c4 + j * 4 + 2] = v.z;
        td[r][c4 + j * 4 + 3] = v.w;
    }
    __syncthreads();
    bf16x8 v0, v1;
#pragma unroll
    for (int i = 0; i < 8; ++i) {
        v0[i] = (short)f2b(td[c4 + i][r]);
        v1[i] = (short)f2b(td[c4 + 8 + i][r]);
    }
    unsigned short* dst = Wt + (long long)(n0 + r) * Dc + k0 + c4;
    *(bf16x8*)dst = v0;
    *(bf16x8*)(dst + 8) = v1;
}

// ---------------- activation transpose: in[16*512][768] bf16 -> outT[16][768][512] bf16 ----------------
__global__ __launch_bounds__(256) void atrans_kernel(const unsigned short* __restrict__ in,
                                                     unsigned short* __restrict__ outT)
{
    __shared__ unsigned short td[64][66];
    const int b = blockIdx.z, s0 = blockIdx.y * 64, n0 = blockIdx.x * 64;
    const int t = threadIdx.x, r = t >> 2, c = (t & 3) * 16;
    const unsigned short* src = in + ((long long)(b * Sc + s0 + r)) * Dc + n0 + c;
    *(bf16x8*)&td[r][c] = *(const bf16x8*)src;
    *(bf16x8*)&td[r][c + 8] = *(const bf16x8*)(src + 8);
    __syncthreads();
    bf16x8 v0, v1;
#pragma unroll
    for (int i = 0; i < 8; ++i) {
        v0[i] = (short)td[c + i][r];
        v1[i] = (short)td[c + 8 + i][r];
    }
    unsigned short* dst = outT + ((long long)b * Dc + n0 + r) * Sc + s0 + c;
    *(bf16x8*)dst = v0;
    *(bf16x8*)(dst + 8) = v1;
}

// ---------------- bf16 MFMA GEMM (both operands [rows][K] row-major; B = "B^T") ----------------
// C[row][col] = act((sum_k A[row][k]*Bt[col][k] + bias[col]) / denom[row])
// Optional comb-epilogue: out = w0*o1 + w1*v with (w0,w1)=softmax(scale_w).
// 128x128 tile, BK=32, 4 waves, global_load_lds staging, 2-barrier loop.
__global__ __launch_bounds__(256) void gemm_bf16(
    const unsigned short* __restrict__ A, const unsigned short* __restrict__ Bt,
    int K, int ldc, long long sA, long long sB, long long sC,
    const float* __restrict__ bias, const float* __restrict__ denom, int relu_flag,
    float* __restrict__ Cf, unsigned short* __restrict__ Cbf, float bscale,
    const unsigned short* __restrict__ comb_o1, const float* __restrict__ scale_w)
{
    const int bz = blockIdx.z;
    A  += (long long)bz * sA;
    Bt += (long long)bz * sB;
    const int row0 = blockIdx.y * 128, col0 = blockIdx.x * 128;

    __shared__ unsigned short Al[128 * 32];
    __shared__ unsigned short Bl[128 * 32];

    const int t = threadIdx.x;
    const int w = t >> 6, l = t & 63, lg = l >> 4, ll = l & 15;
    const int wr = (w >> 1) * 64, wc = (w & 1) * 64;

    f32x4 acc[4][4];
#pragma unroll
    for (int m = 0; m < 4; ++m)
#pragma unroll
        for (int n = 0; n < 4; ++n) acc[m][n] = (f32x4){0.f, 0.f, 0.f, 0.f};

    const unsigned short* Ag = A + (long long)(row0 + (t >> 2)) * K + (t & 3) * 8;
    const unsigned short* Bg = Bt + (long long)(col0 + (t >> 2)) * K + (t & 3) * 8;
    const long long half = 64LL * K;

    for (int k0 = 0; k0 < K; k0 += 32) {
#ifdef HAS_GLLDS
        __syncthreads();  // previous iteration's LDS reads complete
        gl_lds16(Ag + k0, &Al[t * 8]);
        gl_lds16(Ag + half + k0, &Al[2048 + t * 8]);
        gl_lds16(Bg + k0, &Bl[t * 8]);
        gl_lds16(Bg + half + k0, &Bl[2048 + t * 8]);
        __syncthreads();  // drains vmcnt -> LDS tile ready
#else
        const bf16x8 a0 = *(const bf16x8*)(Ag + k0);
        const bf16x8 a1 = *(const bf16x8*)(Ag + half + k0);
        const bf16x8 b0 = *(const bf16x8*)(Bg + k0);
        const bf16x8 b1 = *(const bf16x8*)(Bg + half + k0);
        __syncthreads();
        *(bf16x8*)&Al[t * 8] = a0;
        *(bf16x8*)&Al[2048 + t * 8] = a1;
        *(bf16x8*)&Bl[t * 8] = b0;
        *(bf16x8*)&Bl[2048 + t * 8] = b1;
        __syncthreads();
#endif
        bf16x8 af[4], bv[4];
#pragma unroll
        for (int m = 0; m < 4; ++m)
            af[m] = *(const bf16x8*)&Al[(wr + m * 16 + ll) * 32 + lg * 8];
#pragma unroll
        for (int n = 0; n < 4; ++n)
            bv[n] = *(const bf16x8*)&Bl[(wc + n * 16 + ll) * 32 + lg * 8];
#pragma unroll
        for (int m = 0; m < 4; ++m)
#pragma unroll
            for (int n = 0; n < 4; ++n)
                acc[m][n] = __builtin_amdgcn_mfma_f32_16x16x32_bf16(af[m], bv[n], acc[m][n], 0, 0, 0);
    }

    float w0c = 0.f, w1c = 0.f;
    if (comb_o1) {
        const float s0 = scale_w[0], s1 = scale_w[1];
        const float mx = fmaxf(s0, s1);
        const float e0 = __expf(s0 - mx), e1 = __expf(s1 - mx);
        w0c = e0 / (e0 + e1);
        w1c = e1 / (e0 + e1);
    }

    // epilogue: C/D layout col=ll, row=lg*4+r
#pragma unroll
    for (int m = 0; m < 4; ++m) {
#pragma unroll
        for (int n = 0; n < 4; ++n) {
            const int colg = col0 + wc + n * 16 + ll;
            const float bvl = bias ? bias[colg] : 0.f;
#pragma unroll
            for (int r = 0; r < 4; ++r) {
                const int rowg = row0 + wr + m * 16 + lg * 4 + r;
                float v = acc[m][n][r] + bvl;
                if (denom) v /= denom[rowg];
                if (relu_flag) v = fmaxf(v, 0.f);
                const long long off = (long long)bz * sC + (long long)rowg * ldc + colg;
                if (comb_o1) v = w0c * b2f(comb_o1[off]) + w1c * v;
                if (Cbf) Cbf[off] = f2b(v * bscale);
                if (Cf) Cf[off] = v;
            }
        }
    }
}

// ---------------- qmean: qm[bi][k] = mean_h Qbf[bi][h*96+k] (bf16 out) ----------------
__global__ __launch_bounds__(256) void qmean_kernel(const unsigned short* __restrict__ Qbf,
                                                    unsigned short* __restrict__ qmbf)
{
    const int idx = blockIdx.x * 256 + threadIdx.x;  // 8192*96
    const int bi = idx / DKc, k = idx % DKc;
    const unsigned short* qr = Qbf + (long long)bi * Dc + k;
    float s = 0.f;
#pragma unroll
    for (int h = 0; h < Hc; ++h) s += b2f(qr[h * DKc]);
    qmbf[idx] = f2b(s * 0.125f);
}

// ---------------- rel_emb pad+convert: [257][96] f32 -> [384][96] bf16 (zero pad) ----------------
__global__ __launch_bounds__(256) void relpad_kernel(const float* __restrict__ rel_emb,
                                                     unsigned short* __restrict__ relbf)
{
    const int idx = blockIdx.x * 256 + threadIdx.x;  // 384*96
    const int n = idx / DKc, k = idx % DKc;
    relbf[idx] = (n < 2 * MAXRELc + 1) ? f2b(rel_emb[n * DKc + k]) : (unsigned short)0;
}

// ---------------- Fused adjacency via MFMA ----------------
__global__ __launch_bounds__(256) void adj_mfma_kernel(
    const unsigned short* __restrict__ Qbf, const unsigned short* __restrict__ Kbf,
    const int* __restrict__ tok, const unsigned short* __restrict__ rbb,
    float* __restrict__ adj_out, unsigned short* __restrict__ adjbf_out,
    float* __restrict__ denom_out)
{
    const int b  = blockIdx.x >> 5;
    const int i0 = (blockIdx.x & 31) << 4;
    const int tid = threadIdx.x;
    const int w  = tid >> 6;
    const int l  = tid & 63;
    const int lg = l >> 4;
    const int ll = l & 15;
    const int c0 = w << 7;

    __shared__ float red[4][16];

    const int tokbase = b * Sc;

    float bias[8][4];
    float adjacc[8][4];
#pragma unroll
    for (int f = 0; f < 8; ++f) {
        const int j = c0 + f * 16 + ll;
        const bool km = (tok[tokbase + j] == 0);
#pragma unroll
        for (int r = 0; r < 4; ++r) {
            const int i = i0 + lg * 4 + r;
            int dd = j - i;
            dd = dd < -MAXRELc ? -MAXRELc : (dd > MAXRELc ? MAXRELc : dd);
            bias[f][r] = km ? -1e9f
                            : b2f(rbb[(long long)(tokbase + i) * RBLD + dd + MAXRELc]);
            adjacc[f][r] = 0.f;
        }
    }

    const long long qrow = (long long)(tokbase + i0 + ll) * Dc;

    for (int h = 0; h < Hc; ++h) {
        const int hoff = h * DKc;
        bf16x8 afr[3];
#pragma unroll
        for (int ks = 0; ks < 3; ++ks)
            afr[ks] = *(const bf16x8*)(Qbf + qrow + hoff + ks * 32 + lg * 8);

        float ex[8][4];
        float psum[4] = {0.f, 0.f, 0.f, 0.f};
#pragma unroll
        for (int f = 0; f < 8; ++f) {
            const long long krow = (long long)(tokbase + c0 + f * 16 + ll) * Dc + hoff;
            f32x4 acc = {0.f, 0.f, 0.f, 0.f};
#pragma unroll
            for (int ks = 0; ks < 3; ++ks) {
                const bf16x8 bfr = *(const bf16x8*)(Kbf + krow + ks * 32 + lg * 8);
                acc = __builtin_amdgcn_mfma_f32_16x16x32_bf16(afr[ks], bfr, acc, 0, 0, 0);
            }
#pragma unroll
            for (int r = 0; r < 4; ++r) {
                const float e = __expf(acc[r] + bias[f][r]);
                ex[f][r] = e;
                psum[r] += e;
            }
        }
#pragma unroll
        for (int r = 0; r < 4; ++r) {
            psum[r] += __shfl_xor(psum[r], 1);
            psum[r] += __shfl_xor(psum[r], 2);
            psum[r] += __shfl_xor(psum[r], 4);
            psum[r] += __shfl_xor(psum[r], 8);
        }
        if (ll == 0) {
#pragma unroll
            for (int r = 0; r < 4; ++r) red[w][lg * 4 + r] = psum[r];
        }
        __syncthreads();
#pragma unroll
        for (int r = 0; r < 4; ++r) {
            const int rr = lg * 4 + r;
            const float s = red[0][rr] + red[1][rr] + red[2][rr] + red[3][rr];
            const float inv = 0.125f / s;
#pragma unroll
            for (int f = 0; f < 8; ++f) adjacc[f][r] += ex[f][r] * inv;
        }
        __syncthreads();
    }

    bool rowm[4];
#pragma unroll
    for (int r = 0; r < 4; ++r) rowm[r] = (tok[tokbase + i0 + lg * 4 + r] != 0);

    float psum[4] = {0.f, 0.f, 0.f, 0.f};
#pragma unroll
    for (int f = 0; f < 8; ++f) {
        const int j = c0 + f * 16 + ll;
#pragma unroll
        for (int r = 0; r < 4; ++r) {
            const int i = i0 + lg * 4 + r;
            float v = adjacc[f][r];
            if (j == i) v = 1.f;
            if (!rowm[r]) v = 0.f;
            const long long off = (long long)(tokbase + i) * Sc + j;
            adj_out[off] = v;
            adjbf_out[off] = f2b(v);
            psum[r] += v;
        }
    }
#pragma unroll
    for (int r = 0; r < 4; ++r) {
        psum[r] += __shfl_xor(psum[r], 1);
        psum[r] += __shfl_xor(psum[r], 2);
        psum[r] += __shfl_xor(psum[r], 4);
        psum[r] += __shfl_xor(psum[r], 8);
    }
    if (ll == 0) {
#pragma unroll
        for (int r = 0; r < 4; ++r) red[w][lg * 4 + r] = psum[r];
    }
    __syncthreads();
    if (w == 0 && ll == 0) {
#pragma unroll
        for (int r = 0; r < 4; ++r) {
            const int rr = lg * 4 + r;
            denom_out[tokbase + i0 + rr] =
                red[0][rr] + red[1][rr] + red[2][rr] + red[3][rr] + 1.f;
        }
    }
}

// ---------------- pooling (split + reduce) ----------------
__global__ __launch_bounds__(256) void pool_part_kernel(const float* __restrict__ x,
                                                        float* __restrict__ psum,
                                                        float* __restrict__ pmax)
{
    const int b = blockIdx.z, ct = blockIdx.x, scn = blockIdx.y;
    const int t = threadIdx.x, c = ct * 64 + (t & 63), sg = t >> 6;
    float s = 0.f, m = -INFINITY;
#pragma unroll
    for (int si = 0; si < 16; ++si) {
        const int srow = scn * 64 + sg * 16 + si;
        const float v = x[((long long)(b * Sc + srow)) * Dc + c];
        s += v;
        m = fmaxf(m, v);
    }
    __shared__ float rs[4][64], rm[4][64];
    rs[sg][t & 63] = s;
    rm[sg][t & 63] = m;
    __syncthreads();
    if (t < 64) {
        s = rs[0][t] + rs[1][t] + rs[2][t] + rs[3][t];
        m = fmaxf(fmaxf(rm[0][t], rm[1][t]), fmaxf(rm[2][t], rm[3][t]));
        const long long o = ((long long)b * 8 + scn) * Dc + ct * 64 + t;
        psum[o] = s;
        pmax[o] = m;
    }
}

__global__ __launch_bounds__(256) void pool_red_kernel(const float* __restrict__ psum,
                                                       const float* __restrict__ pmax,
                                                       float* __restrict__ gpool)
{
    const int idx = blockIdx.x * 256 + threadIdx.x;
    const int b = idx / Dc, c = idx % Dc;
    float s = 0.f, m = -INFINITY;
#pragma unroll
    for (int i = 0; i < 8; ++i) {
        const long long o = ((long long)b * 8 + i) * Dc + c;
        s += psum[o];
        m = fmaxf(m, pmax[o]);
    }
    gpool[(long long)b * 1536 + c] = s * (1.f / Sc);
    gpool[(long long)b * 1536 + Dc + c] = m;
}

// ---------------- skinny GEMM: out[16][768] = in[16][K] @ W[K][768] ----------------
__global__ __launch_bounds__(256) void skinny_partial(const float* __restrict__ in,
                                                      const float* __restrict__ W,
                                                      float* __restrict__ part, int K)
{
    __shared__ float sin_[16][96];
    const int t = threadIdx.x;
    const int nt = blockIdx.x, kc = blockIdx.y;
    const int k0 = kc * 96;
    for (int idx = t; idx < 16 * 96; idx += 256) {
        const int b = idx / 96, c = idx % 96;
        sin_[b][c] = in[(long long)b * K + k0 + c];
    }
    __syncthreads();
    const int n = nt * 64 + (t & 63), kg = t >> 6;
    float acc[16];
#pragma unroll
    for (int b = 0; b < 16; ++b) acc[b] = 0.f;
    for (int kk = 0; kk < 24; ++kk) {
        const float wv = W[(long long)(k0 + kg * 24 + kk) * Dc + n];
#pragma unroll
        for (int b = 0; b < 16; ++b) acc[b] += sin_[b][kg * 24 + kk] * wv;
    }
    float* dst = part + ((long long)(kc * 4 + kg) * 16) * Dc + n;
#pragma unroll
    for (int b = 0; b < 16; ++b) dst[(long long)b * Dc] = acc[b];
}

__global__ __launch_bounds__(256) void skinny_reduce(const float* __restrict__ part,
                                                     const float* __restrict__ bias,
                                                     float* __restrict__ outp,
                                                     int nslices, int do_sigmoid)
{
    const int idx = blockIdx.x * 256 + threadIdx.x;
    const int n = idx % Dc;
    float s = bias[n];
    for (int i = 0; i < nslices; ++i) s += part[(long long)i * (16 * Dc) + idx];
    if (do_sigmoid) s = 1.f / (1.f + __expf(-s));
    outp[idx] = s;
}

__global__ __launch_bounds__(256) void final_kernel(const float* __restrict__ x,
                                                    const float* __restrict__ gate,
                                                    const float* __restrict__ gc,
                                                    float* __restrict__ outp)
{
    const long long idx = (long long)blockIdx.x * 256 + threadIdx.x;
    const int c = (int)(idx % Dc);
    const long long bs = idx / Dc;
    const int b = (int)(bs / Sc);
    outp[idx] = x[idx] + gate[b * Dc + c] * gc[b * Dc + c];
}

// ---------------- launch ----------------
extern "C" void kernel_launch(void* const* d_in, const int* in_sizes, int n_in,
                              void* d_out, int out_size, void* d_ws, size_t ws_size,
                              hipStream_t stream)
{
    (void)in_sizes; (void)n_in; (void)out_size; (void)ws_size;

    const float* X       = (const float*)d_in[0];
    const int*   tok     = (const int*)d_in[1];
    const float* Wq      = (const float*)d_in[3];
    const float* bq      = (const float*)d_in[4];
    const float* Wk      = (const float*)d_in[5];
    const float* bk      = (const float*)d_in[6];
    const float* rel_emb = (const float*)d_in[7];
    const float* W0      = (const float*)d_in[8];
    const float* b0      = (const float*)d_in[9];
    const float* W1      = (const float*)d_in[10];
    const float* b1      = (const float*)d_in[11];
    const float* scale_w = (const float*)d_in[12];
    const float* Wf      = (const float*)d_in[13];
    const float* bf      = (const float*)d_in[14];
    const float* Wfc     = (const float*)d_in[15];
    const float* bfc     = (const float*)d_in[16];
    const float* Wg      = (const float*)d_in[17];
    const float* bg      = (const float*)d_in[18];

    float* outp = (float*)d_out;
    const long long NBSD = (long long)Bc * Sc * Dc;   // 6291456
    float* adj = outp + NBSD;

    char* wsb = (char*)d_ws;
    const long long MiB = 1048576LL;
    // R0 [0,12MiB): Xbf (phase 1) -> {rb_bf, qmbf, relbf} (phase 1b) -> smalls (phase 3)
    unsigned short* Xbf   = (unsigned short*)(wsb);
    unsigned short* rb_bf = (unsigned short*)(wsb);                 // 8192*384*2 = 6 MiB
    unsigned short* qmbf  = (unsigned short*)(wsb + 6 * MiB);       // 1.5 MiB
    unsigned short* relbf = (unsigned short*)(wsb + 8 * MiB);       // 72 KiB
    float* gpool   = (float*)(wsb);
    float* gcb     = (float*)(wsb + 128 * 1024);
    float* gate    = (float*)(wsb + 192 * 1024);
    float* poolsum = (float*)(wsb + 256 * 1024);
    float* poolmax = (float*)(wsb + 640 * 1024);
    float* pp1     = (float*)(wsb + 1 * MiB);   // 3 MiB
    float* pp2     = (float*)(wsb + 4 * MiB);   // 1.5 MiB
    // R1 [12,24): Qbf -> combbf
    unsigned short* Qbf    = (unsigned short*)(wsb + 12 * MiB);
    unsigned short* combbf = Qbf;
    // R2 [24,36): Kbf -> out1bf
    unsigned short* Kbf    = (unsigned short*)(wsb + 24 * MiB);
    unsigned short* out1bf = Kbf;
    // R3 [36,48): Xt -> out1t ; xf32 spans [36,60)
    unsigned short* Xt    = (unsigned short*)(wsb + 36 * MiB);
    unsigned short* out1t = Xt;
    float*          xf    = (float*)(wsb + 36 * MiB);
    // R4 [48,56): adjbf
    unsigned short* adjbf = (unsigned short*)(wsb + 48 * MiB);
    // R5 [56,68): Wqt/Wkt (early) -> axbf/ax2bf
    unsigned short* Wqt  = (unsigned short*)(wsb + 56 * MiB);
    unsigned short* Wkt  = (unsigned short*)(wsb + 56 * MiB + 1179648);
    unsigned short* axbf = (unsigned short*)(wsb + 56 * MiB);
    // WT [68,~71.4): persistent weights + denom
    unsigned short* W0t = (unsigned short*)(wsb + 68 * MiB);
    unsigned short* W1t = (unsigned short*)(wsb + 68 * MiB + 1179648);
    unsigned short* Wft = (unsigned short*)(wsb + 68 * MiB + 2359296);
    float*          denom = (float*)(wsb + 68 * MiB + 3538944);

    const float qscale = 0.10206207261596577f;  // 1/sqrt(96)

    auto gemm = [&](const unsigned short* A, const unsigned short* Bt, int M, int N, int K,
                    int ldc, long long sA, long long sB, long long sC, int batch,
                    const float* bias, const float* den, int relu,
                    float* Cf, unsigned short* Cbf, float bscale,
                    const unsigned short* comb_o1, const float* sw) {
        dim3 grid(N / 128, M / 128, batch);
        gemm_bf16<<<grid, 256, 0, stream>>>(A, Bt, K, ldc, sA, sB, sC, bias, den, relu,
                                            Cf, Cbf, bscale, comb_o1, sw);
    };

    // a: X -> bf16
    cvt_bf16_kernel<<<(int)(NBSD / 2048), 256, 0, stream>>>(X, Xbf);
    // b: all 5 weight transposes in one launch
    WT5 wt;
    wt.s[0] = Wq;  wt.d[0] = Wqt;
    wt.s[1] = Wk;  wt.d[1] = Wkt;
    wt.s[2] = W0;  wt.d[2] = W0t;
    wt.s[3] = W1;  wt.d[3] = W1t;
    wt.s[4] = Wf;  wt.d[4] = Wft;
    wtrans5_kernel<<<dim3(12, 12, 5), 256, 0, stream>>>(wt);
    // c,d: Q/K projections (bf16 out; qscale folded into Q)
    gemm(Xbf, Wqt, Bc * Sc, Dc, Dc, Dc, 0, 0, 0, 1, bq, nullptr, 0, nullptr, Qbf, qscale, nullptr, nullptr);
    gemm(Xbf, Wkt, Bc * Sc, Dc, Dc, Dc, 0, 0, 0, 1, bk, nullptr, 0, nullptr, Kbf, 1.f, nullptr, nullptr);
    // e: Xt (transpose while Xbf still live)
    atrans_kernel<<<dim3(12, 8, 16), 256, 0, stream>>>(Xbf, Xt);
    // f,g: qmean + rel pad (overlay Xbf region — Xbf dead now)
    qmean_kernel<<<(Bc * Sc * DKc) / 256, 256, 0, stream>>>(Qbf, qmbf);
    relpad_kernel<<<(RBLD * DKc) / 256, 256, 0, stream>>>(rel_emb, relbf);
    // h: rb = qmean @ rel^T via MFMA GEMM (M=8192, N=384, K=96), bf16 out
    gemm(qmbf, relbf, Bc * Sc, RBLD, DKc, RBLD, 0, 0, 0, 1, nullptr, nullptr, 0,
         nullptr, rb_bf, 1.f, nullptr, nullptr);
    // i: fused adjacency
    adj_mfma_kernel<<<Bc * (Sc / 16), 256, 0, stream>>>(Qbf, Kbf, tok, rb_bf, adj, adjbf, denom);
    // j: ax = adj @ X (batched; B = Xt)
    gemm(adjbf, Xt, Sc, Dc, Sc, Dc, (long long)Sc * Sc, (long long)Dc * Sc, (long long)Sc * Dc,
         Bc, nullptr, nullptr, 0, nullptr, axbf, 1.f, nullptr, nullptr);
    // k: out1 = relu((ax @ W0 + b0)/denom)
    gemm(axbf, W0t, Bc * Sc, Dc, Dc, Dc, 0, 0, 0, 1, b0, denom, 1, nullptr, out1bf, 1.f, nullptr, nullptr);
    // l: out1t
    atrans_kernel<<<dim3(12, 8, 16), 256, 0, stream>>>(out1bf, out1t);
    // m: ax2 = adj @ out1 (batched)
    gemm(adjbf, out1t, Sc, Dc, Sc, Dc, (long long)Sc * Sc, (long long)Dc * Sc, (long long)Sc * Dc,
         Bc, nullptr, nullptr, 0, nullptr, axbf, 1.f, nullptr, nullptr);
    // n: combined = w0*out1 + w1*relu((ax2 @ W1 + b1)/denom)   (comb fused in epilogue)
    gemm(axbf, W1t, Bc * Sc, Dc, Dc, Dc, 0, 0, 0, 1, b1, denom, 1, nullptr, combbf, 1.f,
         out1bf, scale_w);
    // o: x = combined @ Wf + bf (f32)
    gemm(combbf, Wft, Bc * Sc, Dc, Dc, Dc, 0, 0, 0, 1, bf, nullptr, 0, xf, nullptr, 1.f, nullptr, nullptr);
    // p: pooling
    pool_part_kernel<<<dim3(12, 8, 16), 256, 0, stream>>>(xf, poolsum, poolmax);
    pool_red_kernel<<<(Bc * Dc) / 256, 256, 0, stream>>>(poolsum, poolmax, gpool);
    // q: gc = [gavg|gmax] @ Wfc + bfc ; gate = sigmoid(gc @ Wg + bg)
    skinny_partial<<<dim3(12, 16), 256, 0, stream>>>(gpool, Wfc, pp1, 2 * Dc);
    skinny_reduce<<<(Bc * Dc) / 256, 256, 0, stream>>>(pp1, bfc, gcb, 64, 0);
    skinny_partial<<<dim3(12, 8), 256, 0, stream>>>(gcb, Wg, pp2, Dc);
    skinny_reduce<<<(Bc * Dc) / 256, 256, 0, stream>>>(pp2, bg, gate, 32, 1);
    // r: outputs = x + gate*gc
    final_kernel<<<(int)(NBSD / 256), 256, 0, stream>>>(xf, gate, gcb, outp);
}

// Round 6
// 421.927 us; speedup vs baseline: 8.3161x; 1.2100x over previous
//
#include <hip/hip_runtime.h>
#include <hip/hip_bf16.h>
#include <math.h>

// Problem constants
#define Bc 16
#define Sc 512
#define Dc 768
#define Hc 8
#define DKc 96
#define MAXRELc 128
#define RBLD 384  // padded rel-bias table width

typedef __attribute__((ext_vector_type(8))) short bf16x8;
typedef __attribute__((ext_vector_type(4))) float f32x4;

static __device__ __forceinline__ unsigned short f2b(float f) {
    __hip_bfloat16 h = __float2bfloat16(f);
    return *(unsigned short*)&h;
}
static __device__ __forceinline__ float b2f(unsigned short u) {
    union { float f; unsigned v; } x;
    x.v = ((unsigned)u) << 16;
    return x.f;
}

// Fragment-linear offset for Q/K: element (bi, d) with bi = global row (b*512+s),
// d = h*96 + ks*32 + lg*8 + i. A wave's MFMA fragment load becomes base + lane*16B.
static __device__ __forceinline__ long long fl_off(int rowg, int d) {
    const int h = d / 96, rr = d % 96;
    const int ks = rr >> 5, lg = (rr >> 3) & 3, ii = rr & 7;
    return ((((long long)(rowg >> 4) * 8 + h) * 3 + ks) * 4 + lg) * 128 + (rowg & 15) * 8 + ii;
}

// ---- async global->LDS (16B/lane) ----
#if defined(__has_builtin)
#if __has_builtin(__builtin_amdgcn_global_load_lds)
#define HAS_GLLDS 1
#endif
#endif

#ifdef HAS_GLLDS
typedef __attribute__((address_space(1))) void as1_void;
typedef __attribute__((address_space(3))) void as3_void;
static __device__ __forceinline__ void gl_lds16(const void* g, void* l) {
    __builtin_amdgcn_global_load_lds((as1_void*)(unsigned long long)g,
                                     (as3_void*)(unsigned long long)l, 16, 0, 0);
}
#endif

// ---------------- f32 -> bf16 convert ----------------
__global__ __launch_bounds__(256) void cvt_bf16_kernel(const float* __restrict__ in,
                                                       unsigned short* __restrict__ out)
{
    const long long idx = ((long long)blockIdx.x * 256 + threadIdx.x) * 8;
    const float4 a = *(const float4*)(in + idx);
    const float4 b = *(const float4*)(in + idx + 4);
    bf16x8 v;
    v[0] = (short)f2b(a.x); v[1] = (short)f2b(a.y); v[2] = (short)f2b(a.z); v[3] = (short)f2b(a.w);
    v[4] = (short)f2b(b.x); v[5] = (short)f2b(b.y); v[6] = (short)f2b(b.z); v[7] = (short)f2b(b.w);
    *(bf16x8*)(out + idx) = v;
}

// ---------------- 5 weight transposes: W[768][768] f32 -> Wt[768][768] bf16 ----------------
struct WT5 { const float* s[5]; unsigned short* d[5]; };

__global__ __launch_bounds__(256) void wtrans5_kernel(WT5 p)
{
    const float* W = p.s[blockIdx.z];
    unsigned short* Wt = p.d[blockIdx.z];
    __shared__ float td[64][65];
    const int n0 = blockIdx.x * 64, k0 = blockIdx.y * 64;
    const int t = threadIdx.x, r = t >> 2, c4 = (t & 3) * 16;
#pragma unroll
    for (int j = 0; j < 4; ++j) {
        const float4 v = *(const float4*)(W + (long long)(k0 + r) * Dc + n0 + c4 + j * 4);
        td[r][c4 + j * 4 + 0] = v.x;
        td[r][c4 + j * 4 + 1] = v.y;
        td[r][c4 + j * 4 + 2] = v.z;
        td[r][c4 + j * 4 + 3] = v.w;
    }
    __syncthreads();
    bf16x8 v0, v1;
#pragma unroll
    for (int i = 0; i < 8; ++i) {
        v0[i] = (short)f2b(td[c4 + i][r]);
        v1[i] = (short)f2b(td[c4 + 8 + i][r]);
    }
    unsigned short* dst = Wt + (long long)(n0 + r) * Dc + k0 + c4;
    *(bf16x8*)dst = v0;
    *(bf16x8*)(dst + 8) = v1;
}

// ---------------- bias concat: bqk[0..767]=bq, [768..1535]=bk ----------------
__global__ __launch_bounds__(256) void catbias_kernel(const float* __restrict__ a,
                                                      const float* __restrict__ b,
                                                      float* __restrict__ o)
{
    const int i = blockIdx.x * 256 + threadIdx.x;
    o[i] = (i < Dc) ? a[i] : b[i - Dc];
}

// ---------------- activation transpose: [16*512][768] bf16 -> [16][768][512] bf16 ----------------
__global__ __launch_bounds__(256) void atrans_kernel(const unsigned short* __restrict__ in,
                                                     unsigned short* __restrict__ outT)
{
    __shared__ unsigned short td[64][66];
    const int b = blockIdx.z, s0 = blockIdx.y * 64, n0 = blockIdx.x * 64;
    const int t = threadIdx.x, r = t >> 2, c = (t & 3) * 16;
    const unsigned short* src = in + ((long long)(b * Sc + s0 + r)) * Dc + n0 + c;
    *(bf16x8*)&td[r][c] = *(const bf16x8*)src;
    *(bf16x8*)&td[r][c + 8] = *(const bf16x8*)(src + 8);
    __syncthreads();
    bf16x8 v0, v1;
#pragma unroll
    for (int i = 0; i < 8; ++i) {
        v0[i] = (short)td[c + i][r];
        v1[i] = (short)td[c + 8 + i][r];
    }
    unsigned short* dst = outT + ((long long)b * Dc + n0 + r) * Sc + s0 + c;
    *(bf16x8*)dst = v0;
    *(bf16x8*)(dst + 8) = v1;
}

// ---------------- bf16 MFMA GEMM, 128x64 tile, BK=32, 2-phase dbuf pipeline ----------------
// Both operands [rows][K] row-major (B = B^T). 4 waves: wave quadrant 64rows x 32cols.
// qk_mode: N=1536 merged Q|K projection; writes fragment-linear bf16 (Q *= bscale).
__global__ __launch_bounds__(256) void gemm_bf16(
    const unsigned short* __restrict__ A, const unsigned short* __restrict__ Bt,
    int K, int ldc, long long sA, long long sB, long long sC,
    const float* __restrict__ bias, const float* __restrict__ denom, int relu_flag,
    float* __restrict__ Cf, unsigned short* __restrict__ Cbf, float bscale,
    const unsigned short* __restrict__ comb_o1, const float* __restrict__ scale_w,
    int qk_mode, unsigned short* __restrict__ Kfl_out)
{
    const int bz = blockIdx.z;
    A  += (long long)bz * sA;
    Bt += (long long)bz * sB;
    const int row0 = blockIdx.y * 128, col0 = blockIdx.x * 64;

    __shared__ unsigned short Al[2][128 * 32];
    __shared__ unsigned short Bl[2][64 * 32];

    const int t = threadIdx.x;
    const int w = t >> 6, l = t & 63, lg = l >> 4, ll = l & 15;
    const int wr = (w >> 1) * 64, wc = (w & 1) * 32;

    f32x4 acc[4][2];
#pragma unroll
    for (int m = 0; m < 4; ++m)
#pragma unroll
        for (int n = 0; n < 2; ++n) acc[m][n] = (f32x4){0.f, 0.f, 0.f, 0.f};

    const unsigned short* Ag = A + (long long)(row0 + (t >> 2)) * K + (t & 3) * 8;
    const unsigned short* Bg = Bt + (long long)(col0 + (t >> 2)) * K + (t & 3) * 8;
    const long long halfA = 64LL * K;
    const int nt = K >> 5;

#ifdef HAS_GLLDS
    // prologue: stage tile 0
    gl_lds16(Ag, &Al[0][t * 8]);
    gl_lds16(Ag + halfA, &Al[0][2048 + t * 8]);
    gl_lds16(Bg, &Bl[0][t * 8]);
    __syncthreads();
    int cur = 0;
    for (int tt = 0; tt < nt; ++tt) {
        if (tt + 1 < nt) {  // stage next tile into the other buffer (in flight during MFMA)
            const int ko = (tt + 1) << 5;
            gl_lds16(Ag + ko, &Al[cur ^ 1][t * 8]);
            gl_lds16(Ag + halfA + ko, &Al[cur ^ 1][2048 + t * 8]);
            gl_lds16(Bg + ko, &Bl[cur ^ 1][t * 8]);
        }
        bf16x8 af[4], bv[2];
#pragma unroll
        for (int m = 0; m < 4; ++m)
            af[m] = *(const bf16x8*)&Al[cur][(wr + m * 16 + ll) * 32 + lg * 8];
#pragma unroll
        for (int n = 0; n < 2; ++n)
            bv[n] = *(const bf16x8*)&Bl[cur][(wc + n * 16 + ll) * 32 + lg * 8];
#pragma unroll
        for (int m = 0; m < 4; ++m)
#pragma unroll
            for (int n = 0; n < 2; ++n)
                acc[m][n] = __builtin_amdgcn_mfma_f32_16x16x32_bf16(af[m], bv[n], acc[m][n], 0, 0, 0);
        __syncthreads();  // drains vmcnt (next tile landed) + all reads of cur done
        cur ^= 1;
    }
#else
    for (int k0 = 0; k0 < K; k0 += 32) {
        const bf16x8 a0 = *(const bf16x8*)(Ag + k0);
        const bf16x8 a1 = *(const bf16x8*)(Ag + halfA + k0);
        const bf16x8 b0 = *(const bf16x8*)(Bg + k0);
        __syncthreads();
        *(bf16x8*)&Al[0][t * 8] = a0;
        *(bf16x8*)&Al[0][2048 + t * 8] = a1;
        *(bf16x8*)&Bl[0][t * 8] = b0;
        __syncthreads();
        bf16x8 af[4], bv[2];
#pragma unroll
        for (int m = 0; m < 4; ++m)
            af[m] = *(const bf16x8*)&Al[0][(wr + m * 16 + ll) * 32 + lg * 8];
#pragma unroll
        for (int n = 0; n < 2; ++n)
            bv[n] = *(const bf16x8*)&Bl[0][(wc + n * 16 + ll) * 32 + lg * 8];
#pragma unroll
        for (int m = 0; m < 4; ++m)
#pragma unroll
            for (int n = 0; n < 2; ++n)
                acc[m][n] = __builtin_amdgcn_mfma_f32_16x16x32_bf16(af[m], bv[n], acc[m][n], 0, 0, 0);
    }
#endif

    if (qk_mode) {
        // merged Q|K projection epilogue -> fragment-linear layouts
#pragma unroll
        for (int m = 0; m < 4; ++m) {
#pragma unroll
            for (int n = 0; n < 2; ++n) {
                const int colg = col0 + wc + n * 16 + ll;
                const int isQ = colg < Dc;
                const int d = isQ ? colg : colg - Dc;
                const float bvl = bias[colg];
#pragma unroll
                for (int r = 0; r < 4; ++r) {
                    const int rowg = row0 + wr + m * 16 + lg * 4 + r;
                    float v = acc[m][n][r] + bvl;
                    if (isQ) v *= bscale;
                    (isQ ? Cbf : Kfl_out)[fl_off(rowg, d)] = f2b(v);
                }
            }
        }
        return;
    }

    float w0c = 0.f, w1c = 0.f;
    if (comb_o1) {
        const float s0 = scale_w[0], s1 = scale_w[1];
        const float mx = fmaxf(s0, s1);
        const float e0 = __expf(s0 - mx), e1 = __expf(s1 - mx);
        w0c = e0 / (e0 + e1);
        w1c = e1 / (e0 + e1);
    }

    // epilogue: C/D layout col=ll, row=lg*4+r
#pragma unroll
    for (int m = 0; m < 4; ++m) {
#pragma unroll
        for (int n = 0; n < 2; ++n) {
            const int colg = col0 + wc + n * 16 + ll;
            const float bvl = bias ? bias[colg] : 0.f;
#pragma unroll
            for (int r = 0; r < 4; ++r) {
                const int rowg = row0 + wr + m * 16 + lg * 4 + r;
                float v = acc[m][n][r] + bvl;
                if (denom) v /= denom[rowg];
                if (relu_flag) v = fmaxf(v, 0.f);
                const long long off = (long long)bz * sC + (long long)rowg * ldc + colg;
                if (comb_o1) v = w0c * b2f(comb_o1[off]) + w1c * v;
                if (Cbf) Cbf[off] = f2b(v);
                if (Cf) Cf[off] = v;
            }
        }
    }
}

// ---------------- qmean from fragment-linear Q ----------------
__global__ __launch_bounds__(256) void qmean_kernel(const unsigned short* __restrict__ Qfl,
                                                    unsigned short* __restrict__ qmbf)
{
    const int idx = blockIdx.x * 256 + threadIdx.x;  // bi*96 + k
    const int bi = idx / DKc, k = idx % DKc;
    const int g = bi >> 4, llr = bi & 15;
    const int ks = k >> 5, lg = (k >> 3) & 3, ii = k & 7;
    float s = 0.f;
#pragma unroll
    for (int h = 0; h < Hc; ++h)
        s += b2f(Qfl[((((long long)g * 8 + h) * 3 + ks) * 4 + lg) * 128 + llr * 8 + ii]);
    qmbf[idx] = f2b(s * 0.125f);
}

// ---------------- rel_emb pad+convert: [257][96] f32 -> [384][96] bf16 ----------------
__global__ __launch_bounds__(256) void relpad_kernel(const float* __restrict__ rel_emb,
                                                     unsigned short* __restrict__ relbf)
{
    const int idx = blockIdx.x * 256 + threadIdx.x;  // 384*96
    const int n = idx / DKc, k = idx % DKc;
    relbf[idx] = (n < 2 * MAXRELc + 1) ? f2b(rel_emb[n * DKc + k]) : (unsigned short)0;
}

// ---------------- Fused adjacency via MFMA (fragment-linear Q/K: coalesced loads) ----------------
__global__ __launch_bounds__(256) void adj_mfma_kernel(
    const unsigned short* __restrict__ Qfl, const unsigned short* __restrict__ Kfl,
    const int* __restrict__ tok, const unsigned short* __restrict__ rbb,
    float* __restrict__ adj_out, unsigned short* __restrict__ adjbf_out,
    float* __restrict__ denom_out)
{
    const int b  = blockIdx.x >> 5;
    const int i0 = (blockIdx.x & 31) << 4;
    const int tid = threadIdx.x;
    const int w  = tid >> 6;
    const int l  = tid & 63;
    const int lg = l >> 4;
    const int ll = l & 15;
    const int c0 = w << 7;

    __shared__ float red[4][16];

    const int tokbase = b * Sc;
    const int qg  = b * 32 + (i0 >> 4);   // Q fragment group
    const int kgb = b * 32 + w * 8;       // K fragment group base for this wave

    float bias[8][4];
    float adjacc[8][4];
#pragma unroll
    for (int f = 0; f < 8; ++f) {
        const int j = c0 + f * 16 + ll;
        const bool km = (tok[tokbase + j] == 0);
#pragma unroll
        for (int r = 0; r < 4; ++r) {
            const int i = i0 + lg * 4 + r;
            int dd = j - i;
            dd = dd < -MAXRELc ? -MAXRELc : (dd > MAXRELc ? MAXRELc : dd);
            bias[f][r] = km ? -1e9f
                            : b2f(rbb[(long long)(tokbase + i) * RBLD + dd + MAXRELc]);
            adjacc[f][r] = 0.f;
        }
    }

    for (int h = 0; h < Hc; ++h) {
        bf16x8 afr[3];
#pragma unroll
        for (int ks = 0; ks < 3; ++ks)
            afr[ks] = *(const bf16x8*)(Qfl + ((((long long)qg * 8 + h) * 3 + ks) << 9) + l * 8);

        float ex[8][4];
        float psum[4] = {0.f, 0.f, 0.f, 0.f};
#pragma unroll
        for (int f = 0; f < 8; ++f) {
            const long long kbase = (((long long)(kgb + f) * 8 + h) * 3) << 9;
            f32x4 acc = {0.f, 0.f, 0.f, 0.f};
#pragma unroll
            for (int ks = 0; ks < 3; ++ks) {
                const bf16x8 bfr = *(const bf16x8*)(Kfl + kbase + (ks << 9) + l * 8);
                acc = __builtin_amdgcn_mfma_f32_16x16x32_bf16(afr[ks], bfr, acc, 0, 0, 0);
            }
#pragma unroll
            for (int r = 0; r < 4; ++r) {
                const float e = __expf(acc[r] + bias[f][r]);
                ex[f][r] = e;
                psum[r] += e;
            }
        }
#pragma unroll
        for (int r = 0; r < 4; ++r) {
            psum[r] += __shfl_xor(psum[r], 1);
            psum[r] += __shfl_xor(psum[r], 2);
            psum[r] += __shfl_xor(psum[r], 4);
            psum[r] += __shfl_xor(psum[r], 8);
        }
        if (ll == 0) {
#pragma unroll
            for (int r = 0; r < 4; ++r) red[w][lg * 4 + r] = psum[r];
        }
        __syncthreads();
#pragma unroll
        for (int r = 0; r < 4; ++r) {
            const int rr = lg * 4 + r;
            const float s = red[0][rr] + red[1][rr] + red[2][rr] + red[3][rr];
            const float inv = 0.125f / s;
#pragma unroll
            for (int f = 0; f < 8; ++f) adjacc[f][r] += ex[f][r] * inv;
        }
        __syncthreads();
    }

    bool rowm[4];
#pragma unroll
    for (int r = 0; r < 4; ++r) rowm[r] = (tok[tokbase + i0 + lg * 4 + r] != 0);

    float psum[4] = {0.f, 0.f, 0.f, 0.f};
#pragma unroll
    for (int f = 0; f < 8; ++f) {
        const int j = c0 + f * 16 + ll;
#pragma unroll
        for (int r = 0; r < 4; ++r) {
            const int i = i0 + lg * 4 + r;
            float v = adjacc[f][r];
            if (j == i) v = 1.f;
            if (!rowm[r]) v = 0.f;
            const long long off = (long long)(tokbase + i) * Sc + j;
            adj_out[off] = v;
            adjbf_out[off] = f2b(v);
            psum[r] += v;
        }
    }
#pragma unroll
    for (int r = 0; r < 4; ++r) {
        psum[r] += __shfl_xor(psum[r], 1);
        psum[r] += __shfl_xor(psum[r], 2);
        psum[r] += __shfl_xor(psum[r], 4);
        psum[r] += __shfl_xor(psum[r], 8);
    }
    if (ll == 0) {
#pragma unroll
        for (int r = 0; r < 4; ++r) red[w][lg * 4 + r] = psum[r];
    }
    __syncthreads();
    if (w == 0 && ll == 0) {
#pragma unroll
        for (int r = 0; r < 4; ++r) {
            const int rr = lg * 4 + r;
            denom_out[tokbase + i0 + rr] =
                red[0][rr] + red[1][rr] + red[2][rr] + red[3][rr] + 1.f;
        }
    }
}

// ---------------- pooling (split + reduce) ----------------
__global__ __launch_bounds__(256) void pool_part_kernel(const float* __restrict__ x,
                                                        float* __restrict__ psum,
                                                        float* __restrict__ pmax)
{
    const int b = blockIdx.z, ct = blockIdx.x, scn = blockIdx.y;
    const int t = threadIdx.x, c = ct * 64 + (t & 63), sg = t >> 6;
    float s = 0.f, m = -INFINITY;
#pragma unroll
    for (int si = 0; si < 16; ++si) {
        const int srow = scn * 64 + sg * 16 + si;
        const float v = x[((long long)(b * Sc + srow)) * Dc + c];
        s += v;
        m = fmaxf(m, v);
    }
    __shared__ float rs[4][64], rm[4][64];
    rs[sg][t & 63] = s;
    rm[sg][t & 63] = m;
    __syncthreads();
    if (t < 64) {
        s = rs[0][t] + rs[1][t] + rs[2][t] + rs[3][t];
        m = fmaxf(fmaxf(rm[0][t], rm[1][t]), fmaxf(rm[2][t], rm[3][t]));
        const long long o = ((long long)b * 8 + scn) * Dc + ct * 64 + t;
        psum[o] = s;
        pmax[o] = m;
    }
}

__global__ __launch_bounds__(256) void pool_red_kernel(const float* __restrict__ psum,
                                                       const float* __restrict__ pmax,
                                                       float* __restrict__ gpool)
{
    const int idx = blockIdx.x * 256 + threadIdx.x;
    const int b = idx / Dc, c = idx % Dc;
    float s = 0.f, m = -INFINITY;
#pragma unroll
    for (int i = 0; i < 8; ++i) {
        const long long o = ((long long)b * 8 + i) * Dc + c;
        s += psum[o];
        m = fmaxf(m, pmax[o]);
    }
    gpool[(long long)b * 1536 + c] = s * (1.f / Sc);
    gpool[(long long)b * 1536 + Dc + c] = m;
}

// ---------------- skinny GEMM: out[16][768] = in[16][K] @ W[K][768] ----------------
__global__ __launch_bounds__(256) void skinny_partial(const float* __restrict__ in,
                                                      const float* __restrict__ W,
                                                      float* __restrict__ part, int K)
{
    __shared__ float sin_[16][96];
    const int t = threadIdx.x;
    const int nt = blockIdx.x, kc = blockIdx.y;
    const int k0 = kc * 96;
    for (int idx = t; idx < 16 * 96; idx += 256) {
        const int b = idx / 96, c = idx % 96;
        sin_[b][c] = in[(long long)b * K + k0 + c];
    }
    __syncthreads();
    const int n = nt * 64 + (t & 63), kg = t >> 6;
    float acc[16];
#pragma unroll
    for (int b = 0; b < 16; ++b) acc[b] = 0.f;
    for (int kk = 0; kk < 24; ++kk) {
        const float wv = W[(long long)(k0 + kg * 24 + kk) * Dc + n];
#pragma unroll
        for (int b = 0; b < 16; ++b) acc[b] += sin_[b][kg * 24 + kk] * wv;
    }
    float* dst = part + ((long long)(kc * 4 + kg) * 16) * Dc + n;
#pragma unroll
    for (int b = 0; b < 16; ++b) dst[(long long)b * Dc] = acc[b];
}

__global__ __launch_bounds__(256) void skinny_reduce(const float* __restrict__ part,
                                                     const float* __restrict__ bias,
                                                     float* __restrict__ outp,
                                                     int nslices, int do_sigmoid)
{
    const int idx = blockIdx.x * 256 + threadIdx.x;
    const int n = idx % Dc;
    float s = bias[n];
    for (int i = 0; i < nslices; ++i) s += part[(long long)i * (16 * Dc) + idx];
    if (do_sigmoid) s = 1.f / (1.f + __expf(-s));
    outp[idx] = s;
}

__global__ __launch_bounds__(256) void final_kernel(const float* __restrict__ x,
                                                    const float* __restrict__ gate,
                                                    const float* __restrict__ gc,
                                                    float* __restrict__ outp)
{
    const long long idx = (long long)blockIdx.x * 256 + threadIdx.x;
    const int c = (int)(idx % Dc);
    const long long bs = idx / Dc;
    const int b = (int)(bs / Sc);
    outp[idx] = x[idx] + gate[b * Dc + c] * gc[b * Dc + c];
}

// ---------------- launch ----------------
extern "C" void kernel_launch(void* const* d_in, const int* in_sizes, int n_in,
                              void* d_out, int out_size, void* d_ws, size_t ws_size,
                              hipStream_t stream)
{
    (void)in_sizes; (void)n_in; (void)out_size; (void)ws_size;

    const float* X       = (const float*)d_in[0];
    const int*   tok     = (const int*)d_in[1];
    const float* Wq      = (const float*)d_in[3];
    const float* bq      = (const float*)d_in[4];
    const float* Wk      = (const float*)d_in[5];
    const float* bk      = (const float*)d_in[6];
    const float* rel_emb = (const float*)d_in[7];
    const float* W0      = (const float*)d_in[8];
    const float* b0      = (const float*)d_in[9];
    const float* W1      = (const float*)d_in[10];
    const float* b1      = (const float*)d_in[11];
    const float* scale_w = (const float*)d_in[12];
    const float* Wf      = (const float*)d_in[13];
    const float* bf      = (const float*)d_in[14];
    const float* Wfc     = (const float*)d_in[15];
    const float* bfc     = (const float*)d_in[16];
    const float* Wg      = (const float*)d_in[17];
    const float* bg      = (const float*)d_in[18];

    float* outp = (float*)d_out;
    const long long NBSD = (long long)Bc * Sc * Dc;   // 6291456
    float* adj = outp + NBSD;

    char* wsb = (char*)d_ws;
    const long long MiB = 1048576LL;
    // R0 [0,12MiB): Xbf (phase 1) -> {rb_bf, qmbf, relbf} (phase 1b) -> smalls (phase 3)
    unsigned short* Xbf   = (unsigned short*)(wsb);
    unsigned short* rb_bf = (unsigned short*)(wsb);                 // 6 MiB
    unsigned short* qmbf  = (unsigned short*)(wsb + 6 * MiB);       // 1.5 MiB
    unsigned short* relbf = (unsigned short*)(wsb + 8 * MiB);       // 72 KiB
    float* gpool   = (float*)(wsb);
    float* gcb     = (float*)(wsb + 128 * 1024);
    float* gate    = (float*)(wsb + 192 * 1024);
    float* poolsum = (float*)(wsb + 256 * 1024);
    float* poolmax = (float*)(wsb + 640 * 1024);
    float* pp1     = (float*)(wsb + 1 * MiB);   // 3 MiB
    float* pp2     = (float*)(wsb + 4 * MiB);   // 1.5 MiB
    // R1 [12,24): Qfl -> combbf
    unsigned short* Qfl    = (unsigned short*)(wsb + 12 * MiB);
    unsigned short* combbf = Qfl;
    // R2 [24,36): Kfl -> out1bf
    unsigned short* Kfl    = (unsigned short*)(wsb + 24 * MiB);
    unsigned short* out1bf = Kfl;
    // R3 [36,48): Xt -> out1t ; xf32 spans [36,60)
    unsigned short* Xt    = (unsigned short*)(wsb + 36 * MiB);
    unsigned short* out1t = Xt;
    float*          xf    = (float*)(wsb + 36 * MiB);
    // R4 [48,56): adjbf
    unsigned short* adjbf = (unsigned short*)(wsb + 48 * MiB);
    // R5 [56,68): Wqt/Wkt (early; contiguous => merged [1536][768]) -> axbf
    unsigned short* Wqt  = (unsigned short*)(wsb + 56 * MiB);
    unsigned short* Wkt  = (unsigned short*)(wsb + 56 * MiB + 1179648);
    unsigned short* axbf = (unsigned short*)(wsb + 56 * MiB);
    // WT [68MiB..): persistent weights + denom + bqk
    unsigned short* W0t = (unsigned short*)(wsb + 68 * MiB);
    unsigned short* W1t = (unsigned short*)(wsb + 68 * MiB + 1179648);
    unsigned short* Wft = (unsigned short*)(wsb + 68 * MiB + 2359296);
    float*          denom = (float*)(wsb + 68 * MiB + 3538944);
    float*          bqk   = (float*)(wsb + 68 * MiB + 3538944 + 32768);

    const float qscale = 0.10206207261596577f;  // 1/sqrt(96)

    auto gemm = [&](const unsigned short* A, const unsigned short* Bt, int M, int N, int K,
                    int ldc, long long sA, long long sB, long long sC, int batch,
                    const float* bias, const float* den, int relu,
                    float* Cf, unsigned short* Cbf, float bscale,
                    const unsigned short* comb_o1, const float* sw,
                    int qk_mode, unsigned short* Kfl_out) {
        dim3 grid(N / 64, M / 128, batch);
        gemm_bf16<<<grid, 256, 0, stream>>>(A, Bt, K, ldc, sA, sB, sC, bias, den, relu,
                                            Cf, Cbf, bscale, comb_o1, sw, qk_mode, Kfl_out);
    };

    // a: X -> bf16
    cvt_bf16_kernel<<<(int)(NBSD / 2048), 256, 0, stream>>>(X, Xbf);
    // b: all 5 weight transposes + bias concat
    WT5 wt;
    wt.s[0] = Wq;  wt.d[0] = Wqt;
    wt.s[1] = Wk;  wt.d[1] = Wkt;
    wt.s[2] = W0;  wt.d[2] = W0t;
    wt.s[3] = W1;  wt.d[3] = W1t;
    wt.s[4] = Wf;  wt.d[4] = Wft;
    wtrans5_kernel<<<dim3(12, 12, 5), 256, 0, stream>>>(wt);
    catbias_kernel<<<6, 256, 0, stream>>>(bq, bk, bqk);
    // c: merged Q|K projection (N=1536) -> fragment-linear Qfl/Kfl, qscale folded into Q
    gemm(Xbf, Wqt, Bc * Sc, 2 * Dc, Dc, 0, 0, 0, 0, 1, bqk, nullptr, 0,
         nullptr, Qfl, qscale, nullptr, nullptr, 1, Kfl);
    // e: Xt (transpose while Xbf still live)
    atrans_kernel<<<dim3(12, 8, 16), 256, 0, stream>>>(Xbf, Xt);
    // f,g: qmean + rel pad (overlay Xbf region — Xbf dead now)
    qmean_kernel<<<(Bc * Sc * DKc) / 256, 256, 0, stream>>>(Qfl, qmbf);
    relpad_kernel<<<(RBLD * DKc) / 256, 256, 0, stream>>>(rel_emb, relbf);
    // h: rb = qmean @ rel^T (M=8192, N=384, K=96), bf16 row-major out
    gemm(qmbf, relbf, Bc * Sc, RBLD, DKc, RBLD, 0, 0, 0, 1, nullptr, nullptr, 0,
         nullptr, rb_bf, 1.f, nullptr, nullptr, 0, nullptr);
    // i: fused adjacency
    adj_mfma_kernel<<<Bc * (Sc / 16), 256, 0, stream>>>(Qfl, Kfl, tok, rb_bf, adj, adjbf, denom);
    // j: ax = adj @ X (batched; B = Xt)
    gemm(adjbf, Xt, Sc, Dc, Sc, Dc, (long long)Sc * Sc, (long long)Dc * Sc, (long long)Sc * Dc,
         Bc, nullptr, nullptr, 0, nullptr, axbf, 1.f, nullptr, nullptr, 0, nullptr);
    // k: out1 = relu((ax @ W0 + b0)/denom)
    gemm(axbf, W0t, Bc * Sc, Dc, Dc, Dc, 0, 0, 0, 1, b0, denom, 1,
         nullptr, out1bf, 1.f, nullptr, nullptr, 0, nullptr);
    // l: out1t
    atrans_kernel<<<dim3(12, 8, 16), 256, 0, stream>>>(out1bf, out1t);
    // m: ax2 = adj @ out1 (batched)
    gemm(adjbf, out1t, Sc, Dc, Sc, Dc, (long long)Sc * Sc, (long long)Dc * Sc, (long long)Sc * Dc,
         Bc, nullptr, nullptr, 0, nullptr, axbf, 1.f, nullptr, nullptr, 0, nullptr);
    // n: combined = w0*out1 + w1*relu((ax2 @ W1 + b1)/denom)  (comb fused)
    gemm(axbf, W1t, Bc * Sc, Dc, Dc, Dc, 0, 0, 0, 1, b1, denom, 1,
         nullptr, combbf, 1.f, out1bf, scale_w, 0, nullptr);
    // o: x = combined @ Wf + bf (f32)
    gemm(combbf, Wft, Bc * Sc, Dc, Dc, Dc, 0, 0, 0, 1, bf, nullptr, 0,
         xf, nullptr, 1.f, nullptr, nullptr, 0, nullptr);
    // p: pooling
    pool_part_kernel<<<dim3(12, 8, 16), 256, 0, stream>>>(xf, poolsum, poolmax);
    pool_red_kernel<<<(Bc * Dc) / 256, 256, 0, stream>>>(poolsum, poolmax, gpool);
    // q: gc = [gavg|gmax] @ Wfc + bfc ; gate = sigmoid(gc @ Wg + bg)
    skinny_partial<<<dim3(12, 16), 256, 0, stream>>>(gpool, Wfc, pp1, 2 * Dc);
    skinny_reduce<<<(Bc * Dc) / 256, 256, 0, stream>>>(pp1, bfc, gcb, 64, 0);
    skinny_partial<<<dim3(12, 8), 256, 0, stream>>>(gcb, Wg, pp2, Dc);
    skinny_reduce<<<(Bc * Dc) / 256, 256, 0, stream>>>(pp2, bg, gate, 32, 1);
    // r: outputs = x + gate*gc
    final_kernel<<<(int)(NBSD / 256), 256, 0, stream>>>(xf, gate, gcb, outp);
}

// Round 7
// 420.831 us; speedup vs baseline: 8.3378x; 1.0026x over previous
//
#include <hip/hip_runtime.h>
#include <hip/hip_bf16.h>
#include <math.h>

// Problem constants
#define Bc 16
#define Sc 512
#define Dc 768
#define Hc 8
#define DKc 96
#define MAXRELc 128
#define RBLD 384  // padded rel-bias table width

typedef __attribute__((ext_vector_type(8))) short bf16x8;
typedef __attribute__((ext_vector_type(4))) float f32x4;

static __device__ __forceinline__ unsigned short f2b(float f) {
    __hip_bfloat16 h = __float2bfloat16(f);
    return *(unsigned short*)&h;
}
static __device__ __forceinline__ float b2f(unsigned short u) {
    union { float f; unsigned v; } x;
    x.v = ((unsigned)u) << 16;
    return x.f;
}

// Fragment-linear offset for Q/K: element (bi, d) with bi = global row (b*512+s),
// d = h*96 + ks*32 + lg*8 + i. A wave's MFMA fragment load becomes base + lane*16B.
static __device__ __forceinline__ long long fl_off(int rowg, int d) {
    const int h = d / 96, rr = d % 96;
    const int ks = rr >> 5, lg = (rr >> 3) & 3, ii = rr & 7;
    return ((((long long)(rowg >> 4) * 8 + h) * 3 + ks) * 4 + lg) * 128 + (rowg & 15) * 8 + ii;
}

// ---- async global->LDS (16B/lane) ----
#if defined(__has_builtin)
#if __has_builtin(__builtin_amdgcn_global_load_lds)
#define HAS_GLLDS 1
#endif
#endif

#ifdef HAS_GLLDS
typedef __attribute__((address_space(1))) void as1_void;
typedef __attribute__((address_space(3))) void as3_void;
static __device__ __forceinline__ void gl_lds16(const void* g, void* l) {
    __builtin_amdgcn_global_load_lds((as1_void*)(unsigned long long)g,
                                     (as3_void*)(unsigned long long)l, 16, 0, 0);
}
#endif

// LDS bank-conflict swizzle (both-sides, rule #21):
// logical fragment (row, lg) lives at LDS slot s = (lg + (row>>1)) & 3.
// Staging lane t writes LDS location (row=t>>2, slot=t&3) linearly, so its
// GLOBAL k-slot is the inverse permutation ((t&3) - (t>>3)) & 3.
#define SWS(row, lg) (((((lg) + ((row) >> 1)) & 3)) * 8)

// ---------------- f32 -> bf16 convert ----------------
__global__ __launch_bounds__(256) void cvt_bf16_kernel(const float* __restrict__ in,
                                                       unsigned short* __restrict__ out)
{
    const long long idx = ((long long)blockIdx.x * 256 + threadIdx.x) * 8;
    const float4 a = *(const float4*)(in + idx);
    const float4 b = *(const float4*)(in + idx + 4);
    bf16x8 v;
    v[0] = (short)f2b(a.x); v[1] = (short)f2b(a.y); v[2] = (short)f2b(a.z); v[3] = (short)f2b(a.w);
    v[4] = (short)f2b(b.x); v[5] = (short)f2b(b.y); v[6] = (short)f2b(b.z); v[7] = (short)f2b(b.w);
    *(bf16x8*)(out + idx) = v;
}

// ---------------- 5 weight transposes: W[768][768] f32 -> Wt[768][768] bf16 ----------------
struct WT5 { const float* s[5]; unsigned short* d[5]; };

__global__ __launch_bounds__(256) void wtrans5_kernel(WT5 p)
{
    const float* W = p.s[blockIdx.z];
    unsigned short* Wt = p.d[blockIdx.z];
    __shared__ float td[64][65];
    const int n0 = blockIdx.x * 64, k0 = blockIdx.y * 64;
    const int t = threadIdx.x, r = t >> 2, c4 = (t & 3) * 16;
#pragma unroll
    for (int j = 0; j < 4; ++j) {
        const float4 v = *(const float4*)(W + (long long)(k0 + r) * Dc + n0 + c4 + j * 4);
        td[r][c4 + j * 4 + 0] = v.x;
        td[r][c4 + j * 4 + 1] = v.y;
        td[r][c4 + j * 4 + 2] = v.z;
        td[r][c4 + j * 4 + 3] = v.w;
    }
    __syncthreads();
    bf16x8 v0, v1;
#pragma unroll
    for (int i = 0; i < 8; ++i) {
        v0[i] = (short)f2b(td[c4 + i][r]);
        v1[i] = (short)f2b(td[c4 + 8 + i][r]);
    }
    unsigned short* dst = Wt + (long long)(n0 + r) * Dc + k0 + c4;
    *(bf16x8*)dst = v0;
    *(bf16x8*)(dst + 8) = v1;
}

// ---------------- bias concat: bqk[0..767]=bq, [768..1535]=bk ----------------
__global__ __launch_bounds__(256) void catbias_kernel(const float* __restrict__ a,
                                                      const float* __restrict__ b,
                                                      float* __restrict__ o)
{
    const int i = blockIdx.x * 256 + threadIdx.x;
    o[i] = (i < Dc) ? a[i] : b[i - Dc];
}

// ---------------- activation transpose: [16*512][768] bf16 -> [16][768][512] bf16 ----------------
__global__ __launch_bounds__(256) void atrans_kernel(const unsigned short* __restrict__ in,
                                                     unsigned short* __restrict__ outT)
{
    __shared__ unsigned short td[64][66];
    const int b = blockIdx.z, s0 = blockIdx.y * 64, n0 = blockIdx.x * 64;
    const int t = threadIdx.x, r = t >> 2, c = (t & 3) * 16;
    const unsigned short* src = in + ((long long)(b * Sc + s0 + r)) * Dc + n0 + c;
    *(bf16x8*)&td[r][c] = *(const bf16x8*)src;
    *(bf16x8*)&td[r][c + 8] = *(const bf16x8*)(src + 8);
    __syncthreads();
    bf16x8 v0, v1;
#pragma unroll
    for (int i = 0; i < 8; ++i) {
        v0[i] = (short)td[c + i][r];
        v1[i] = (short)td[c + 8 + i][r];
    }
    unsigned short* dst = outT + ((long long)b * Dc + n0 + r) * Sc + s0 + c;
    *(bf16x8*)dst = v0;
    *(bf16x8*)(dst + 8) = v1;
}

// ---------------- bf16 MFMA GEMM, 128x64 tile, BK=32, 2-phase dbuf + LDS swizzle ----------------
// Both operands [rows][K] row-major (B = B^T). 4 waves: wave quadrant 64rows x 32cols.
// qk_mode: N=1536 merged Q|K projection; writes fragment-linear bf16 (Q *= bscale).
__global__ __launch_bounds__(256) void gemm_bf16(
    const unsigned short* __restrict__ A, const unsigned short* __restrict__ Bt,
    int K, int ldc, long long sA, long long sB, long long sC,
    const float* __restrict__ bias, const float* __restrict__ denom, int relu_flag,
    float* __restrict__ Cf, unsigned short* __restrict__ Cbf, float bscale,
    const unsigned short* __restrict__ comb_o1, const float* __restrict__ scale_w,
    int qk_mode, unsigned short* __restrict__ Kfl_out)
{
    const int bz = blockIdx.z;
    A  += (long long)bz * sA;
    Bt += (long long)bz * sB;
    const int row0 = blockIdx.y * 128, col0 = blockIdx.x * 64;

    __shared__ unsigned short Al[2][128 * 32];
    __shared__ unsigned short Bl[2][64 * 32];

    const int t = threadIdx.x;
    const int w = t >> 6, l = t & 63, lg = l >> 4, ll = l & 15;
    const int wr = (w >> 1) * 64, wc = (w & 1) * 32;

    f32x4 acc[4][2];
#pragma unroll
    for (int m = 0; m < 4; ++m)
#pragma unroll
        for (int n = 0; n < 2; ++n) acc[m][n] = (f32x4){0.f, 0.f, 0.f, 0.f};

    // inverse-swizzled global k-slot for this staging lane (elements)
    const int ksw = (((t & 3) - (t >> 3)) & 3) * 8;
    const unsigned short* Ag = A + (long long)(row0 + (t >> 2)) * K + ksw;
    const unsigned short* Bg = Bt + (long long)(col0 + (t >> 2)) * K + ksw;
    const long long halfA = 64LL * K;
    const int nt = K >> 5;

#ifdef HAS_GLLDS
    // prologue: stage tile 0
    gl_lds16(Ag, &Al[0][t * 8]);
    gl_lds16(Ag + halfA, &Al[0][2048 + t * 8]);
    gl_lds16(Bg, &Bl[0][t * 8]);
    __syncthreads();
    int cur = 0;
    for (int tt = 0; tt < nt; ++tt) {
        if (tt + 1 < nt) {  // stage next tile into the other buffer (in flight during MFMA)
            const int ko = (tt + 1) << 5;
            gl_lds16(Ag + ko, &Al[cur ^ 1][t * 8]);
            gl_lds16(Ag + halfA + ko, &Al[cur ^ 1][2048 + t * 8]);
            gl_lds16(Bg + ko, &Bl[cur ^ 1][t * 8]);
        }
        bf16x8 af[4], bv[2];
#pragma unroll
        for (int m = 0; m < 4; ++m) {
            const int row = wr + m * 16 + ll;
            af[m] = *(const bf16x8*)&Al[cur][row * 32 + SWS(row, lg)];
        }
#pragma unroll
        for (int n = 0; n < 2; ++n) {
            const int row = wc + n * 16 + ll;
            bv[n] = *(const bf16x8*)&Bl[cur][row * 32 + SWS(row, lg)];
        }
#pragma unroll
        for (int m = 0; m < 4; ++m)
#pragma unroll
            for (int n = 0; n < 2; ++n)
                acc[m][n] = __builtin_amdgcn_mfma_f32_16x16x32_bf16(af[m], bv[n], acc[m][n], 0, 0, 0);
        __syncthreads();  // drains vmcnt (next tile landed) + all reads of cur done
        cur ^= 1;
    }
#else
    for (int k0 = 0; k0 < K; k0 += 32) {
        const bf16x8 a0 = *(const bf16x8*)(Ag + k0);
        const bf16x8 a1 = *(const bf16x8*)(Ag + halfA + k0);
        const bf16x8 b0 = *(const bf16x8*)(Bg + k0);
        __syncthreads();
        *(bf16x8*)&Al[0][t * 8] = a0;
        *(bf16x8*)&Al[0][2048 + t * 8] = a1;
        *(bf16x8*)&Bl[0][t * 8] = b0;
        __syncthreads();
        bf16x8 af[4], bv[2];
#pragma unroll
        for (int m = 0; m < 4; ++m) {
            const int row = wr + m * 16 + ll;
            af[m] = *(const bf16x8*)&Al[0][row * 32 + SWS(row, lg)];
        }
#pragma unroll
        for (int n = 0; n < 2; ++n) {
            const int row = wc + n * 16 + ll;
            bv[n] = *(const bf16x8*)&Bl[0][row * 32 + SWS(row, lg)];
        }
#pragma unroll
        for (int m = 0; m < 4; ++m)
#pragma unroll
            for (int n = 0; n < 2; ++n)
                acc[m][n] = __builtin_amdgcn_mfma_f32_16x16x32_bf16(af[m], bv[n], acc[m][n], 0, 0, 0);
    }
#endif

    if (qk_mode) {
        // merged Q|K projection epilogue -> fragment-linear layouts
#pragma unroll
        for (int m = 0; m < 4; ++m) {
#pragma unroll
            for (int n = 0; n < 2; ++n) {
                const int colg = col0 + wc + n * 16 + ll;
                const int isQ = colg < Dc;
                const int d = isQ ? colg : colg - Dc;
                const float bvl = bias[colg];
#pragma unroll
                for (int r = 0; r < 4; ++r) {
                    const int rowg = row0 + wr + m * 16 + lg * 4 + r;
                    float v = acc[m][n][r] + bvl;
                    if (isQ) v *= bscale;
                    (isQ ? Cbf : Kfl_out)[fl_off(rowg, d)] = f2b(v);
                }
            }
        }
        return;
    }

    float w0c = 0.f, w1c = 0.f;
    if (comb_o1) {
        const float s0 = scale_w[0], s1 = scale_w[1];
        const float mx = fmaxf(s0, s1);
        const float e0 = __expf(s0 - mx), e1 = __expf(s1 - mx);
        w0c = e0 / (e0 + e1);
        w1c = e1 / (e0 + e1);
    }

    // epilogue: C/D layout col=ll, row=lg*4+r
#pragma unroll
    for (int m = 0; m < 4; ++m) {
#pragma unroll
        for (int n = 0; n < 2; ++n) {
            const int colg = col0 + wc + n * 16 + ll;
            const float bvl = bias ? bias[colg] : 0.f;
#pragma unroll
            for (int r = 0; r < 4; ++r) {
                const int rowg = row0 + wr + m * 16 + lg * 4 + r;
                float v = acc[m][n][r] + bvl;
                if (denom) v /= denom[rowg];
                if (relu_flag) v = fmaxf(v, 0.f);
                const long long off = (long long)bz * sC + (long long)rowg * ldc + colg;
                if (comb_o1) v = w0c * b2f(comb_o1[off]) + w1c * v;
                if (Cbf) Cbf[off] = f2b(v);
                if (Cf) Cf[off] = v;
            }
        }
    }
}

// ---------------- qmean from fragment-linear Q ----------------
__global__ __launch_bounds__(256) void qmean_kernel(const unsigned short* __restrict__ Qfl,
                                                    unsigned short* __restrict__ qmbf)
{
    const int idx = blockIdx.x * 256 + threadIdx.x;  // bi*96 + k
    const int bi = idx / DKc, k = idx % DKc;
    const int g = bi >> 4, llr = bi & 15;
    const int ks = k >> 5, lg = (k >> 3) & 3, ii = k & 7;
    float s = 0.f;
#pragma unroll
    for (int h = 0; h < Hc; ++h)
        s += b2f(Qfl[((((long long)g * 8 + h) * 3 + ks) * 4 + lg) * 128 + llr * 8 + ii]);
    qmbf[idx] = f2b(s * 0.125f);
}

// ---------------- rel_emb pad+convert: [257][96] f32 -> [384][96] bf16 ----------------
__global__ __launch_bounds__(256) void relpad_kernel(const float* __restrict__ rel_emb,
                                                     unsigned short* __restrict__ relbf)
{
    const int idx = blockIdx.x * 256 + threadIdx.x;  // 384*96
    const int n = idx / DKc, k = idx % DKc;
    relbf[idx] = (n < 2 * MAXRELc + 1) ? f2b(rel_emb[n * DKc + k]) : (unsigned short)0;
}

// ---------------- Fused adjacency via MFMA (fragment-linear Q/K: coalesced loads) ----------------
__global__ __launch_bounds__(256) void adj_mfma_kernel(
    const unsigned short* __restrict__ Qfl, const unsigned short* __restrict__ Kfl,
    const int* __restrict__ tok, const unsigned short* __restrict__ rbb,
    float* __restrict__ adj_out, unsigned short* __restrict__ adjbf_out,
    float* __restrict__ denom_out)
{
    const int b  = blockIdx.x >> 5;
    const int i0 = (blockIdx.x & 31) << 4;
    const int tid = threadIdx.x;
    const int w  = tid >> 6;
    const int l  = tid & 63;
    const int lg = l >> 4;
    const int ll = l & 15;
    const int c0 = w << 7;

    __shared__ float red[4][16];

    const int tokbase = b * Sc;
    const int qg  = b * 32 + (i0 >> 4);   // Q fragment group
    const int kgb = b * 32 + w * 8;       // K fragment group base for this wave

    float bias[8][4];
    float adjacc[8][4];
#pragma unroll
    for (int f = 0; f < 8; ++f) {
        const int j = c0 + f * 16 + ll;
        const bool km = (tok[tokbase + j] == 0);
#pragma unroll
        for (int r = 0; r < 4; ++r) {
            const int i = i0 + lg * 4 + r;
            int dd = j - i;
            dd = dd < -MAXRELc ? -MAXRELc : (dd > MAXRELc ? MAXRELc : dd);
            bias[f][r] = km ? -1e9f
                            : b2f(rbb[(long long)(tokbase + i) * RBLD + dd + MAXRELc]);
            adjacc[f][r] = 0.f;
        }
    }

    for (int h = 0; h < Hc; ++h) {
        bf16x8 afr[3];
#pragma unroll
        for (int ks = 0; ks < 3; ++ks)
            afr[ks] = *(const bf16x8*)(Qfl + ((((long long)qg * 8 + h) * 3 + ks) << 9) + l * 8);

        float ex[8][4];
        float psum[4] = {0.f, 0.f, 0.f, 0.f};
#pragma unroll
        for (int f = 0; f < 8; ++f) {
            const long long kbase = (((long long)(kgb + f) * 8 + h) * 3) << 9;
            f32x4 acc = {0.f, 0.f, 0.f, 0.f};
#pragma unroll
            for (int ks = 0; ks < 3; ++ks) {
                const bf16x8 bfr = *(const bf16x8*)(Kfl + kbase + (ks << 9) + l * 8);
                acc = __builtin_amdgcn_mfma_f32_16x16x32_bf16(afr[ks], bfr, acc, 0, 0, 0);
            }
#pragma unroll
            for (int r = 0; r < 4; ++r) {
                const float e = __expf(acc[r] + bias[f][r]);
                ex[f][r] = e;
                psum[r] += e;
            }
        }
#pragma unroll
        for (int r = 0; r < 4; ++r) {
            psum[r] += __shfl_xor(psum[r], 1);
            psum[r] += __shfl_xor(psum[r], 2);
            psum[r] += __shfl_xor(psum[r], 4);
            psum[r] += __shfl_xor(psum[r], 8);
        }
        if (ll == 0) {
#pragma unroll
            for (int r = 0; r < 4; ++r) red[w][lg * 4 + r] = psum[r];
        }
        __syncthreads();
#pragma unroll
        for (int r = 0; r < 4; ++r) {
            const int rr = lg * 4 + r;
            const float s = red[0][rr] + red[1][rr] + red[2][rr] + red[3][rr];
            const float inv = 0.125f / s;
#pragma unroll
            for (int f = 0; f < 8; ++f) adjacc[f][r] += ex[f][r] * inv;
        }
        __syncthreads();
    }

    bool rowm[4];
#pragma unroll
    for (int r = 0; r < 4; ++r) rowm[r] = (tok[tokbase + i0 + lg * 4 + r] != 0);

    float psum[4] = {0.f, 0.f, 0.f, 0.f};
#pragma unroll
    for (int f = 0; f < 8; ++f) {
        const int j = c0 + f * 16 + ll;
#pragma unroll
        for (int r = 0; r < 4; ++r) {
            const int i = i0 + lg * 4 + r;
            float v = adjacc[f][r];
            if (j == i) v = 1.f;
            if (!rowm[r]) v = 0.f;
            const long long off = (long long)(tokbase + i) * Sc + j;
            adj_out[off] = v;
            adjbf_out[off] = f2b(v);
            psum[r] += v;
        }
    }
#pragma unroll
    for (int r = 0; r < 4; ++r) {
        psum[r] += __shfl_xor(psum[r], 1);
        psum[r] += __shfl_xor(psum[r], 2);
        psum[r] += __shfl_xor(psum[r], 4);
        psum[r] += __shfl_xor(psum[r], 8);
    }
    if (ll == 0) {
#pragma unroll
        for (int r = 0; r < 4; ++r) red[w][lg * 4 + r] = psum[r];
    }
    __syncthreads();
    if (w == 0 && ll == 0) {
#pragma unroll
        for (int r = 0; r < 4; ++r) {
            const int rr = lg * 4 + r;
            denom_out[tokbase + i0 + rr] =
                red[0][rr] + red[1][rr] + red[2][rr] + red[3][rr] + 1.f;
        }
    }
}

// ---------------- pooling (split + reduce) ----------------
__global__ __launch_bounds__(256) void pool_part_kernel(const float* __restrict__ x,
                                                        float* __restrict__ psum,
                                                        float* __restrict__ pmax)
{
    const int b = blockIdx.z, ct = blockIdx.x, scn = blockIdx.y;
    const int t = threadIdx.x, c = ct * 64 + (t & 63), sg = t >> 6;
    float s = 0.f, m = -INFINITY;
#pragma unroll
    for (int si = 0; si < 16; ++si) {
        const int srow = scn * 64 + sg * 16 + si;
        const float v = x[((long long)(b * Sc + srow)) * Dc + c];
        s += v;
        m = fmaxf(m, v);
    }
    __shared__ float rs[4][64], rm[4][64];
    rs[sg][t & 63] = s;
    rm[sg][t & 63] = m;
    __syncthreads();
    if (t < 64) {
        s = rs[0][t] + rs[1][t] + rs[2][t] + rs[3][t];
        m = fmaxf(fmaxf(rm[0][t], rm[1][t]), fmaxf(rm[2][t], rm[3][t]));
        const long long o = ((long long)b * 8 + scn) * Dc + ct * 64 + t;
        psum[o] = s;
        pmax[o] = m;
    }
}

__global__ __launch_bounds__(256) void pool_red_kernel(const float* __restrict__ psum,
                                                       const float* __restrict__ pmax,
                                                       float* __restrict__ gpool)
{
    const int idx = blockIdx.x * 256 + threadIdx.x;
    const int b = idx / Dc, c = idx % Dc;
    float s = 0.f, m = -INFINITY;
#pragma unroll
    for (int i = 0; i < 8; ++i) {
        const long long o = ((long long)b * 8 + i) * Dc + c;
        s += psum[o];
        m = fmaxf(m, pmax[o]);
    }
    gpool[(long long)b * 1536 + c] = s * (1.f / Sc);
    gpool[(long long)b * 1536 + Dc + c] = m;
}

// ---------------- skinny GEMM: out[16][768] = in[16][K] @ W[K][768] ----------------
__global__ __launch_bounds__(256) void skinny_partial(const float* __restrict__ in,
                                                      const float* __restrict__ W,
                                                      float* __restrict__ part, int K)
{
    __shared__ float sin_[16][96];
    const int t = threadIdx.x;
    const int nt = blockIdx.x, kc = blockIdx.y;
    const int k0 = kc * 96;
    for (int idx = t; idx < 16 * 96; idx += 256) {
        const int b = idx / 96, c = idx % 96;
        sin_[b][c] = in[(long long)b * K + k0 + c];
    }
    __syncthreads();
    const int n = nt * 64 + (t & 63), kg = t >> 6;
    float acc[16];
#pragma unroll
    for (int b = 0; b < 16; ++b) acc[b] = 0.f;
    for (int kk = 0; kk < 24; ++kk) {
        const float wv = W[(long long)(k0 + kg * 24 + kk) * Dc + n];
#pragma unroll
        for (int b = 0; b < 16; ++b) acc[b] += sin_[b][kg * 24 + kk] * wv;
    }
    float* dst = part + ((long long)(kc * 4 + kg) * 16) * Dc + n;
#pragma unroll
    for (int b = 0; b < 16; ++b) dst[(long long)b * Dc] = acc[b];
}

__global__ __launch_bounds__(256) void skinny_reduce(const float* __restrict__ part,
                                                     const float* __restrict__ bias,
                                                     float* __restrict__ outp,
                                                     int nslices, int do_sigmoid)
{
    const int idx = blockIdx.x * 256 + threadIdx.x;
    const int n = idx % Dc;
    float s = bias[n];
    for (int i = 0; i < nslices; ++i) s += part[(long long)i * (16 * Dc) + idx];
    if (do_sigmoid) s = 1.f / (1.f + __expf(-s));
    outp[idx] = s;
}

__global__ __launch_bounds__(256) void final_kernel(const float* __restrict__ x,
                                                    const float* __restrict__ gate,
                                                    const float* __restrict__ gc,
                                                    float* __restrict__ outp)
{
    const long long idx = (long long)blockIdx.x * 256 + threadIdx.x;
    const int c = (int)(idx % Dc);
    const long long bs = idx / Dc;
    const int b = (int)(bs / Sc);
    outp[idx] = x[idx] + gate[b * Dc + c] * gc[b * Dc + c];
}

// ---------------- launch ----------------
extern "C" void kernel_launch(void* const* d_in, const int* in_sizes, int n_in,
                              void* d_out, int out_size, void* d_ws, size_t ws_size,
                              hipStream_t stream)
{
    (void)in_sizes; (void)n_in; (void)out_size; (void)ws_size;

    const float* X       = (const float*)d_in[0];
    const int*   tok     = (const int*)d_in[1];
    const float* Wq      = (const float*)d_in[3];
    const float* bq      = (const float*)d_in[4];
    const float* Wk      = (const float*)d_in[5];
    const float* bk      = (const float*)d_in[6];
    const float* rel_emb = (const float*)d_in[7];
    const float* W0      = (const float*)d_in[8];
    const float* b0      = (const float*)d_in[9];
    const float* W1      = (const float*)d_in[10];
    const float* b1      = (const float*)d_in[11];
    const float* scale_w = (const float*)d_in[12];
    const float* Wf      = (const float*)d_in[13];
    const float* bf      = (const float*)d_in[14];
    const float* Wfc     = (const float*)d_in[15];
    const float* bfc     = (const float*)d_in[16];
    const float* Wg      = (const float*)d_in[17];
    const float* bg      = (const float*)d_in[18];

    float* outp = (float*)d_out;
    const long long NBSD = (long long)Bc * Sc * Dc;   // 6291456
    float* adj = outp + NBSD;

    char* wsb = (char*)d_ws;
    const long long MiB = 1048576LL;
    // R0 [0,12MiB): Xbf (phase 1) -> {rb_bf, qmbf, relbf} (phase 1b) -> smalls (phase 3)
    unsigned short* Xbf   = (unsigned short*)(wsb);
    unsigned short* rb_bf = (unsigned short*)(wsb);                 // 6 MiB
    unsigned short* qmbf  = (unsigned short*)(wsb + 6 * MiB);       // 1.5 MiB
    unsigned short* relbf = (unsigned short*)(wsb + 8 * MiB);       // 72 KiB
    float* gpool   = (float*)(wsb);
    float* gcb     = (float*)(wsb + 128 * 1024);
    float* gate    = (float*)(wsb + 192 * 1024);
    float* poolsum = (float*)(wsb + 256 * 1024);
    float* poolmax = (float*)(wsb + 640 * 1024);
    float* pp1     = (float*)(wsb + 1 * MiB);   // 3 MiB
    float* pp2     = (float*)(wsb + 4 * MiB);   // 1.5 MiB
    // R1 [12,24): Qfl -> combbf
    unsigned short* Qfl    = (unsigned short*)(wsb + 12 * MiB);
    unsigned short* combbf = Qfl;
    // R2 [24,36): Kfl -> out1bf
    unsigned short* Kfl    = (unsigned short*)(wsb + 24 * MiB);
    unsigned short* out1bf = Kfl;
    // R3 [36,48): Xt -> out1t ; xf32 spans [36,60)
    unsigned short* Xt    = (unsigned short*)(wsb + 36 * MiB);
    unsigned short* out1t = Xt;
    float*          xf    = (float*)(wsb + 36 * MiB);
    // R4 [48,56): adjbf
    unsigned short* adjbf = (unsigned short*)(wsb + 48 * MiB);
    // R5 [56,68): Wqt/Wkt (early; contiguous => merged [1536][768]) -> axbf
    unsigned short* Wqt  = (unsigned short*)(wsb + 56 * MiB);
    unsigned short* Wkt  = (unsigned short*)(wsb + 56 * MiB + 1179648);
    unsigned short* axbf = (unsigned short*)(wsb + 56 * MiB);
    // WT [68MiB..): persistent weights + denom + bqk
    unsigned short* W0t = (unsigned short*)(wsb + 68 * MiB);
    unsigned short* W1t = (unsigned short*)(wsb + 68 * MiB + 1179648);
    unsigned short* Wft = (unsigned short*)(wsb + 68 * MiB + 2359296);
    float*          denom = (float*)(wsb + 68 * MiB + 3538944);
    float*          bqk   = (float*)(wsb + 68 * MiB + 3538944 + 32768);

    const float qscale = 0.10206207261596577f;  // 1/sqrt(96)

    auto gemm = [&](const unsigned short* A, const unsigned short* Bt, int M, int N, int K,
                    int ldc, long long sA, long long sB, long long sC, int batch,
                    const float* bias, const float* den, int relu,
                    float* Cf, unsigned short* Cbf, float bscale,
                    const unsigned short* comb_o1, const float* sw,
                    int qk_mode, unsigned short* Kfl_out) {
        dim3 grid(N / 64, M / 128, batch);
        gemm_bf16<<<grid, 256, 0, stream>>>(A, Bt, K, ldc, sA, sB, sC, bias, den, relu,
                                            Cf, Cbf, bscale, comb_o1, sw, qk_mode, Kfl_out);
    };

    // a: X -> bf16
    cvt_bf16_kernel<<<(int)(NBSD / 2048), 256, 0, stream>>>(X, Xbf);
    // b: all 5 weight transposes + bias concat
    WT5 wt;
    wt.s[0] = Wq;  wt.d[0] = Wqt;
    wt.s[1] = Wk;  wt.d[1] = Wkt;
    wt.s[2] = W0;  wt.d[2] = W0t;
    wt.s[3] = W1;  wt.d[3] = W1t;
    wt.s[4] = Wf;  wt.d[4] = Wft;
    wtrans5_kernel<<<dim3(12, 12, 5), 256, 0, stream>>>(wt);
    catbias_kernel<<<6, 256, 0, stream>>>(bq, bk, bqk);
    // c: merged Q|K projection (N=1536) -> fragment-linear Qfl/Kfl, qscale folded into Q
    gemm(Xbf, Wqt, Bc * Sc, 2 * Dc, Dc, 0, 0, 0, 0, 1, bqk, nullptr, 0,
         nullptr, Qfl, qscale, nullptr, nullptr, 1, Kfl);
    // e: Xt (transpose while Xbf still live)
    atrans_kernel<<<dim3(12, 8, 16), 256, 0, stream>>>(Xbf, Xt);
    // f,g: qmean + rel pad (overlay Xbf region — Xbf dead now)
    qmean_kernel<<<(Bc * Sc * DKc) / 256, 256, 0, stream>>>(Qfl, qmbf);
    relpad_kernel<<<(RBLD * DKc) / 256, 256, 0, stream>>>(rel_emb, relbf);
    // h: rb = qmean @ rel^T (M=8192, N=384, K=96), bf16 row-major out
    gemm(qmbf, relbf, Bc * Sc, RBLD, DKc, RBLD, 0, 0, 0, 1, nullptr, nullptr, 0,
         nullptr, rb_bf, 1.f, nullptr, nullptr, 0, nullptr);
    // i: fused adjacency
    adj_mfma_kernel<<<Bc * (Sc / 16), 256, 0, stream>>>(Qfl, Kfl, tok, rb_bf, adj, adjbf, denom);
    // j: ax = adj @ X (batched; B = Xt)
    gemm(adjbf, Xt, Sc, Dc, Sc, Dc, (long long)Sc * Sc, (long long)Dc * Sc, (long long)Sc * Dc,
         Bc, nullptr, nullptr, 0, nullptr, axbf, 1.f, nullptr, nullptr, 0, nullptr);
    // k: out1 = relu((ax @ W0 + b0)/denom)
    gemm(axbf, W0t, Bc * Sc, Dc, Dc, Dc, 0, 0, 0, 1, b0, denom, 1,
         nullptr, out1bf, 1.f, nullptr, nullptr, 0, nullptr);
    // l: out1t
    atrans_kernel<<<dim3(12, 8, 16), 256, 0, stream>>>(out1bf, out1t);
    // m: ax2 = adj @ out1 (batched)
    gemm(adjbf, out1t, Sc, Dc, Sc, Dc, (long long)Sc * Sc, (long long)Dc * Sc, (long long)Sc * Dc,
         Bc, nullptr, nullptr, 0, nullptr, axbf, 1.f, nullptr, nullptr, 0, nullptr);
    // n: combined = w0*out1 + w1*relu((ax2 @ W1 + b1)/denom)  (comb fused)
    gemm(axbf, W1t, Bc * Sc, Dc, Dc, Dc, 0, 0, 0, 1, b1, denom, 1,
         nullptr, combbf, 1.f, out1bf, scale_w, 0, nullptr);
    // o: x = combined @ Wf + bf (f32)
    gemm(combbf, Wft, Bc * Sc, Dc, Dc, Dc, 0, 0, 0, 1, bf, nullptr, 0,
         xf, nullptr, 1.f, nullptr, nullptr, 0, nullptr);
    // p: pooling
    pool_part_kernel<<<dim3(12, 8, 16), 256, 0, stream>>>(xf, poolsum, poolmax);
    pool_red_kernel<<<(Bc * Dc) / 256, 256, 0, stream>>>(poolsum, poolmax, gpool);
    // q: gc = [gavg|gmax] @ Wfc + bfc ; gate = sigmoid(gc @ Wg + bg)
    skinny_partial<<<dim3(12, 16), 256, 0, stream>>>(gpool, Wfc, pp1, 2 * Dc);
    skinny_reduce<<<(Bc * Dc) / 256, 256, 0, stream>>>(pp1, bfc, gcb, 64, 0);
    skinny_partial<<<dim3(12, 8), 256, 0, stream>>>(gcb, Wg, pp2, Dc);
    skinny_reduce<<<(Bc * Dc) / 256, 256, 0, stream>>>(pp2, bg, gate, 32, 1);
    // r: outputs = x + gate*gc
    final_kernel<<<(int)(NBSD / 256), 256, 0, stream>>>(xf, gate, gcb, outp);
}

// Round 8
// 405.860 us; speedup vs baseline: 8.6454x; 1.0369x over previous
//
#include <hip/hip_runtime.h>
#include <hip/hip_bf16.h>
#include <math.h>

// Problem constants
#define Bc 16
#define Sc 512
#define Dc 768
#define Hc 8
#define DKc 96
#define MAXRELc 128
#define RBLD 384  // padded rel-bias table width

typedef __attribute__((ext_vector_type(8))) short bf16x8;
typedef __attribute__((ext_vector_type(4))) float f32x4;

static __device__ __forceinline__ unsigned short f2b(float f) {
    __hip_bfloat16 h = __float2bfloat16(f);
    return *(unsigned short*)&h;
}
static __device__ __forceinline__ float b2f(unsigned short u) {
    union { float f; unsigned v; } x;
    x.v = ((unsigned)u) << 16;
    return x.f;
}

// Fragment-linear offset for Q/K: element (bi, d) with bi = global row (b*512+s),
// d = h*96 + ks*32 + lg*8 + i. A wave's MFMA fragment load becomes base + lane*16B.
static __device__ __forceinline__ long long fl_off(int rowg, int d) {
    const int h = d / 96, rr = d % 96;
    const int ks = rr >> 5, lg = (rr >> 3) & 3, ii = rr & 7;
    return ((((long long)(rowg >> 4) * 8 + h) * 3 + ks) * 4 + lg) * 128 + (rowg & 15) * 8 + ii;
}

// ---- async global->LDS (16B/lane) ----
#if defined(__has_builtin)
#if __has_builtin(__builtin_amdgcn_global_load_lds)
#define HAS_GLLDS 1
#endif
#endif

#ifdef HAS_GLLDS
typedef __attribute__((address_space(1))) void as1_void;
typedef __attribute__((address_space(3))) void as3_void;
static __device__ __forceinline__ void gl_lds16(const void* g, void* l) {
    __builtin_amdgcn_global_load_lds((as1_void*)(unsigned long long)g,
                                     (as3_void*)(unsigned long long)l, 16, 0, 0);
}
#endif

// LDS bank-conflict swizzle (both-sides, verified r6: conflicts 3.5M -> 0):
// logical fragment (row, lg) lives at LDS slot s = (lg + (row>>1)) & 3.
// Staging lane t writes LDS location (row=t>>2, slot=t&3) linearly, so its
// GLOBAL k-slot is the inverse permutation ((t&3) - (t>>3)) & 3.
#define SWS(row, lg) (((((lg) + ((row) >> 1)) & 3)) * 8)

// ---------------- f32 -> bf16 convert ----------------
__global__ __launch_bounds__(256) void cvt_bf16_kernel(const float* __restrict__ in,
                                                       unsigned short* __restrict__ out)
{
    const long long idx = ((long long)blockIdx.x * 256 + threadIdx.x) * 8;
    const float4 a = *(const float4*)(in + idx);
    const float4 b = *(const float4*)(in + idx + 4);
    bf16x8 v;
    v[0] = (short)f2b(a.x); v[1] = (short)f2b(a.y); v[2] = (short)f2b(a.z); v[3] = (short)f2b(a.w);
    v[4] = (short)f2b(b.x); v[5] = (short)f2b(b.y); v[6] = (short)f2b(b.z); v[7] = (short)f2b(b.w);
    *(bf16x8*)(out + idx) = v;
}

// ---------------- 5 weight transposes: W[768][768] f32 -> Wt[768][768] bf16 ----------------
struct WT5 { const float* s[5]; unsigned short* d[5]; };

__global__ __launch_bounds__(256) void wtrans5_kernel(WT5 p)
{
    const float* W = p.s[blockIdx.z];
    unsigned short* Wt = p.d[blockIdx.z];
    __shared__ float td[64][65];
    const int n0 = blockIdx.x * 64, k0 = blockIdx.y * 64;
    const int t = threadIdx.x, r = t >> 2, c4 = (t & 3) * 16;
#pragma unroll
    for (int j = 0; j < 4; ++j) {
        const float4 v = *(const float4*)(W + (long long)(k0 + r) * Dc + n0 + c4 + j * 4);
        td[r][c4 + j * 4 + 0] = v.x;
        td[r][c4 + j * 4 + 1] = v.y;
        td[r][c4 + j * 4 + 2] = v.z;
        td[r][c4 + j * 4 + 3] = v.w;
    }
    __syncthreads();
    bf16x8 v0, v1;
#pragma unroll
    for (int i = 0; i < 8; ++i) {
        v0[i] = (short)f2b(td[c4 + i][r]);
        v1[i] = (short)f2b(td[c4 + 8 + i][r]);
    }
    unsigned short* dst = Wt + (long long)(n0 + r) * Dc + k0 + c4;
    *(bf16x8*)dst = v0;
    *(bf16x8*)(dst + 8) = v1;
}

// ---------------- bias concat: bqk[0..767]=bq, [768..1535]=bk ----------------
__global__ __launch_bounds__(256) void catbias_kernel(const float* __restrict__ a,
                                                      const float* __restrict__ b,
                                                      float* __restrict__ o)
{
    const int i = blockIdx.x * 256 + threadIdx.x;
    o[i] = (i < Dc) ? a[i] : b[i - Dc];
}

// ---------------- activation transpose: [16*512][768] bf16 -> [16][768][512] bf16 ----------------
__global__ __launch_bounds__(256) void atrans_kernel(const unsigned short* __restrict__ in,
                                                     unsigned short* __restrict__ outT)
{
    __shared__ unsigned short td[64][66];
    const int b = blockIdx.z, s0 = blockIdx.y * 64, n0 = blockIdx.x * 64;
    const int t = threadIdx.x, r = t >> 2, c = (t & 3) * 16;
    const unsigned short* src = in + ((long long)(b * Sc + s0 + r)) * Dc + n0 + c;
    *(bf16x8*)&td[r][c] = *(const bf16x8*)src;
    *(bf16x8*)&td[r][c + 8] = *(const bf16x8*)(src + 8);
    __syncthreads();
    bf16x8 v0, v1;
#pragma unroll
    for (int i = 0; i < 8; ++i) {
        v0[i] = (short)td[c + i][r];
        v1[i] = (short)td[c + 8 + i][r];
    }
    unsigned short* dst = outT + ((long long)b * Dc + n0 + r) * Sc + s0 + c;
    *(bf16x8*)dst = v0;
    *(bf16x8*)(dst + 8) = v1;
}

// ---------------- bf16 MFMA GEMM, 128x64 tile, BK=32 ----------------
// 3-buffer pipeline, counted vmcnt (loads stay in flight across barriers),
// raw s_barrier, XCD-aware block swizzle. Both operands [rows][K] (B = B^T).
// qk_mode: N=1536 merged Q|K projection; writes fragment-linear bf16 (Q *= bscale).
__global__ __launch_bounds__(256) void gemm_bf16(
    const unsigned short* __restrict__ A, const unsigned short* __restrict__ Bt,
    int K, int ldc, long long sA, long long sB, long long sC,
    const float* __restrict__ bias, const float* __restrict__ denom, int relu_flag,
    float* __restrict__ Cf, unsigned short* __restrict__ Cbf, float bscale,
    const unsigned short* __restrict__ comb_o1, const float* __restrict__ scale_w,
    int qk_mode, unsigned short* __restrict__ Kfl_out)
{
    // XCD-aware bijective swizzle (all grids are multiples of 8 blocks):
    // hardware flat id f -> XCD f%8 gets contiguous semantic chunk.
    const int gx = gridDim.x, gy = gridDim.y;
    const int nwg = gx * gy * gridDim.z;
    int lin = (blockIdx.z * gy + blockIdx.y) * gx + blockIdx.x;
    lin = (lin & 7) * (nwg >> 3) + (lin >> 3);
    const int bx = lin % gx;
    const int rem = lin / gx;
    const int by = rem % gy;
    const int bz = rem / gy;

    A  += (long long)bz * sA;
    Bt += (long long)bz * sB;
    const int row0 = by * 128, col0 = bx * 64;

    __shared__ unsigned short Al[3][128 * 32];
    __shared__ unsigned short Bl[3][64 * 32];

    const int t = threadIdx.x;
    const int w = t >> 6, l = t & 63, lg = l >> 4, ll = l & 15;
    const int wr = (w >> 1) * 64, wc = (w & 1) * 32;

    f32x4 acc[4][2];
#pragma unroll
    for (int m = 0; m < 4; ++m)
#pragma unroll
        for (int n = 0; n < 2; ++n) acc[m][n] = (f32x4){0.f, 0.f, 0.f, 0.f};

    // inverse-swizzled global k-slot for this staging lane (elements)
    const int ksw = (((t & 3) - (t >> 3)) & 3) * 8;
    const unsigned short* Ag = A + (long long)(row0 + (t >> 2)) * K + ksw;
    const unsigned short* Bg = Bt + (long long)(col0 + (t >> 2)) * K + ksw;
    const long long halfA = 64LL * K;
    const int nt = K >> 5;

#ifdef HAS_GLLDS
    // prologue: stage tiles 0 and 1 (6 loads in flight)
    gl_lds16(Ag, &Al[0][t * 8]);
    gl_lds16(Ag + halfA, &Al[0][2048 + t * 8]);
    gl_lds16(Bg, &Bl[0][t * 8]);
    if (nt > 1) {
        gl_lds16(Ag + 32, &Al[1][t * 8]);
        gl_lds16(Ag + halfA + 32, &Al[1][2048 + t * 8]);
        gl_lds16(Bg + 32, &Bl[1][t * 8]);
    }
    for (int tt = 0; tt < nt; ++tt) {
        const int cur = tt % 3;
        // wait for tile tt only (tile tt+1's 3 loads may stay in flight), then align waves
        if (tt + 1 < nt) {
            asm volatile("s_waitcnt vmcnt(3)\n\ts_barrier" ::: "memory");
        } else {
            asm volatile("s_waitcnt vmcnt(0)\n\ts_barrier" ::: "memory");
        }
        bf16x8 af[4], bv[2];
#pragma unroll
        for (int m = 0; m < 4; ++m) {
            const int row = wr + m * 16 + ll;
            af[m] = *(const bf16x8*)&Al[cur][row * 32 + SWS(row, lg)];
        }
#pragma unroll
        for (int n = 0; n < 2; ++n) {
            const int row = wc + n * 16 + ll;
            bv[n] = *(const bf16x8*)&Bl[cur][row * 32 + SWS(row, lg)];
        }
        // drain LDS reads before issuing writes that will eventually land in
        // buffer (tt+2)%3 (avoids pending-read vs async-LDS-write hazard)
        asm volatile("s_waitcnt lgkmcnt(0)" ::: "memory");
        if (tt + 2 < nt) {
            const int ko = (tt + 2) << 5;
            const int nxt = (tt + 2) % 3;
            gl_lds16(Ag + ko, &Al[nxt][t * 8]);
            gl_lds16(Ag + halfA + ko, &Al[nxt][2048 + t * 8]);
            gl_lds16(Bg + ko, &Bl[nxt][t * 8]);
        }
#pragma unroll
        for (int m = 0; m < 4; ++m)
#pragma unroll
            for (int n = 0; n < 2; ++n)
                acc[m][n] = __builtin_amdgcn_mfma_f32_16x16x32_bf16(af[m], bv[n], acc[m][n], 0, 0, 0);
    }
#else
    for (int k0 = 0; k0 < K; k0 += 32) {
        const bf16x8 a0 = *(const bf16x8*)(Ag + k0);
        const bf16x8 a1 = *(const bf16x8*)(Ag + halfA + k0);
        const bf16x8 b0 = *(const bf16x8*)(Bg + k0);
        __syncthreads();
        *(bf16x8*)&Al[0][t * 8] = a0;
        *(bf16x8*)&Al[0][2048 + t * 8] = a1;
        *(bf16x8*)&Bl[0][t * 8] = b0;
        __syncthreads();
        bf16x8 af[4], bv[2];
#pragma unroll
        for (int m = 0; m < 4; ++m) {
            const int row = wr + m * 16 + ll;
            af[m] = *(const bf16x8*)&Al[0][row * 32 + SWS(row, lg)];
        }
#pragma unroll
        for (int n = 0; n < 2; ++n) {
            const int row = wc + n * 16 + ll;
            bv[n] = *(const bf16x8*)&Bl[0][row * 32 + SWS(row, lg)];
        }
#pragma unroll
        for (int m = 0; m < 4; ++m)
#pragma unroll
            for (int n = 0; n < 2; ++n)
                acc[m][n] = __builtin_amdgcn_mfma_f32_16x16x32_bf16(af[m], bv[n], acc[m][n], 0, 0, 0);
    }
#endif

    if (qk_mode) {
        // merged Q|K projection epilogue -> fragment-linear layouts
#pragma unroll
        for (int m = 0; m < 4; ++m) {
#pragma unroll
            for (int n = 0; n < 2; ++n) {
                const int colg = col0 + wc + n * 16 + ll;
                const int isQ = colg < Dc;
                const int d = isQ ? colg : colg - Dc;
                const float bvl = bias[colg];
#pragma unroll
                for (int r = 0; r < 4; ++r) {
                    const int rowg = row0 + wr + m * 16 + lg * 4 + r;
                    float v = acc[m][n][r] + bvl;
                    if (isQ) v *= bscale;
                    (isQ ? Cbf : Kfl_out)[fl_off(rowg, d)] = f2b(v);
                }
            }
        }
        return;
    }

    float w0c = 0.f, w1c = 0.f;
    if (comb_o1) {
        const float s0 = scale_w[0], s1 = scale_w[1];
        const float mx = fmaxf(s0, s1);
        const float e0 = __expf(s0 - mx), e1 = __expf(s1 - mx);
        w0c = e0 / (e0 + e1);
        w1c = e1 / (e0 + e1);
    }

    // epilogue: C/D layout col=ll, row=lg*4+r
#pragma unroll
    for (int m = 0; m < 4; ++m) {
#pragma unroll
        for (int n = 0; n < 2; ++n) {
            const int colg = col0 + wc + n * 16 + ll;
            const float bvl = bias ? bias[colg] : 0.f;
#pragma unroll
            for (int r = 0; r < 4; ++r) {
                const int rowg = row0 + wr + m * 16 + lg * 4 + r;
                float v = acc[m][n][r] + bvl;
                if (denom) v /= denom[rowg];
                if (relu_flag) v = fmaxf(v, 0.f);
                const long long off = (long long)bz * sC + (long long)rowg * ldc + colg;
                if (comb_o1) v = w0c * b2f(comb_o1[off]) + w1c * v;
                if (Cbf) Cbf[off] = f2b(v);
                if (Cf) Cf[off] = v;
            }
        }
    }
}

// ---------------- qmean from fragment-linear Q ----------------
__global__ __launch_bounds__(256) void qmean_kernel(const unsigned short* __restrict__ Qfl,
                                                    unsigned short* __restrict__ qmbf)
{
    const int idx = blockIdx.x * 256 + threadIdx.x;  // bi*96 + k
    const int bi = idx / DKc, k = idx % DKc;
    const int g = bi >> 4, llr = bi & 15;
    const int ks = k >> 5, lg = (k >> 3) & 3, ii = k & 7;
    float s = 0.f;
#pragma unroll
    for (int h = 0; h < Hc; ++h)
        s += b2f(Qfl[((((long long)g * 8 + h) * 3 + ks) * 4 + lg) * 128 + llr * 8 + ii]);
    qmbf[idx] = f2b(s * 0.125f);
}

// ---------------- rel_emb pad+convert: [257][96] f32 -> [384][96] bf16 ----------------
__global__ __launch_bounds__(256) void relpad_kernel(const float* __restrict__ rel_emb,
                                                     unsigned short* __restrict__ relbf)
{
    const int idx = blockIdx.x * 256 + threadIdx.x;  // 384*96
    const int n = idx / DKc, k = idx % DKc;
    relbf[idx] = (n < 2 * MAXRELc + 1) ? f2b(rel_emb[n * DKc + k]) : (unsigned short)0;
}

// ---------------- Fused adjacency via MFMA (fragment-linear Q/K: coalesced loads) ----------------
__global__ __launch_bounds__(256) void adj_mfma_kernel(
    const unsigned short* __restrict__ Qfl, const unsigned short* __restrict__ Kfl,
    const int* __restrict__ tok, const unsigned short* __restrict__ rbb,
    float* __restrict__ adj_out, unsigned short* __restrict__ adjbf_out,
    float* __restrict__ denom_out)
{
    const int b  = blockIdx.x >> 5;
    const int i0 = (blockIdx.x & 31) << 4;
    const int tid = threadIdx.x;
    const int w  = tid >> 6;
    const int l  = tid & 63;
    const int lg = l >> 4;
    const int ll = l & 15;
    const int c0 = w << 7;

    __shared__ float red[4][16];

    const int tokbase = b * Sc;
    const int qg  = b * 32 + (i0 >> 4);   // Q fragment group
    const int kgb = b * 32 + w * 8;       // K fragment group base for this wave

    float bias[8][4];
    float adjacc[8][4];
#pragma unroll
    for (int f = 0; f < 8; ++f) {
        const int j = c0 + f * 16 + ll;
        const bool km = (tok[tokbase + j] == 0);
#pragma unroll
        for (int r = 0; r < 4; ++r) {
            const int i = i0 + lg * 4 + r;
            int dd = j - i;
            dd = dd < -MAXRELc ? -MAXRELc : (dd > MAXRELc ? MAXRELc : dd);
            bias[f][r] = km ? -1e9f
                            : b2f(rbb[(long long)(tokbase + i) * RBLD + dd + MAXRELc]);
            adjacc[f][r] = 0.f;
        }
    }

    for (int h = 0; h < Hc; ++h) {
        bf16x8 afr[3];
#pragma unroll
        for (int ks = 0; ks < 3; ++ks)
            afr[ks] = *(const bf16x8*)(Qfl + ((((long long)qg * 8 + h) * 3 + ks) << 9) + l * 8);

        float ex[8][4];
        float psum[4] = {0.f, 0.f, 0.f, 0.f};
#pragma unroll
        for (int f = 0; f < 8; ++f) {
            const long long kbase = (((long long)(kgb + f) * 8 + h) * 3) << 9;
            f32x4 acc = {0.f, 0.f, 0.f, 0.f};
#pragma unroll
            for (int ks = 0; ks < 3; ++ks) {
                const bf16x8 bfr = *(const bf16x8*)(Kfl + kbase + (ks << 9) + l * 8);
                acc = __builtin_amdgcn_mfma_f32_16x16x32_bf16(afr[ks], bfr, acc, 0, 0, 0);
            }
#pragma unroll
            for (int r = 0; r < 4; ++r) {
                const float e = __expf(acc[r] + bias[f][r]);
                ex[f][r] = e;
                psum[r] += e;
            }
        }
#pragma unroll
        for (int r = 0; r < 4; ++r) {
            psum[r] += __shfl_xor(psum[r], 1);
            psum[r] += __shfl_xor(psum[r], 2);
            psum[r] += __shfl_xor(psum[r], 4);
            psum[r] += __shfl_xor(psum[r], 8);
        }
        if (ll == 0) {
#pragma unroll
            for (int r = 0; r < 4; ++r) red[w][lg * 4 + r] = psum[r];
        }
        __syncthreads();
#pragma unroll
        for (int r = 0; r < 4; ++r) {
            const int rr = lg * 4 + r;
            const float s = red[0][rr] + red[1][rr] + red[2][rr] + red[3][rr];
            const float inv = 0.125f / s;
#pragma unroll
            for (int f = 0; f < 8; ++f) adjacc[f][r] += ex[f][r] * inv;
        }
        __syncthreads();
    }

    bool rowm[4];
#pragma unroll
    for (int r = 0; r < 4; ++r) rowm[r] = (tok[tokbase + i0 + lg * 4 + r] != 0);

    float psum[4] = {0.f, 0.f, 0.f, 0.f};
#pragma unroll
    for (int f = 0; f < 8; ++f) {
        const int j = c0 + f * 16 + ll;
#pragma unroll
        for (int r = 0; r < 4; ++r) {
            const int i = i0 + lg * 4 + r;
            float v = adjacc[f][r];
            if (j == i) v = 1.f;
            if (!rowm[r]) v = 0.f;
            const long long off = (long long)(tokbase + i) * Sc + j;
            adj_out[off] = v;
            adjbf_out[off] = f2b(v);
            psum[r] += v;
        }
    }
#pragma unroll
    for (int r = 0; r < 4; ++r) {
        psum[r] += __shfl_xor(psum[r], 1);
        psum[r] += __shfl_xor(psum[r], 2);
        psum[r] += __shfl_xor(psum[r], 4);
        psum[r] += __shfl_xor(psum[r], 8);
    }
    if (ll == 0) {
#pragma unroll
        for (int r = 0; r < 4; ++r) red[w][lg * 4 + r] = psum[r];
    }
    __syncthreads();
    if (w == 0 && ll == 0) {
#pragma unroll
        for (int r = 0; r < 4; ++r) {
            const int rr = lg * 4 + r;
            denom_out[tokbase + i0 + rr] =
                red[0][rr] + red[1][rr] + red[2][rr] + red[3][rr] + 1.f;
        }
    }
}

// ---------------- pooling (split + reduce) ----------------
__global__ __launch_bounds__(256) void pool_part_kernel(const float* __restrict__ x,
                                                        float* __restrict__ psum,
                                                        float* __restrict__ pmax)
{
    const int b = blockIdx.z, ct = blockIdx.x, scn = blockIdx.y;
    const int t = threadIdx.x, c = ct * 64 + (t & 63), sg = t >> 6;
    float s = 0.f, m = -INFINITY;
#pragma unroll
    for (int si = 0; si < 16; ++si) {
        const int srow = scn * 64 + sg * 16 + si;
        const float v = x[((long long)(b * Sc + srow)) * Dc + c];
        s += v;
        m = fmaxf(m, v);
    }
    __shared__ float rs[4][64], rm[4][64];
    rs[sg][t & 63] = s;
    rm[sg][t & 63] = m;
    __syncthreads();
    if (t < 64) {
        s = rs[0][t] + rs[1][t] + rs[2][t] + rs[3][t];
        m = fmaxf(fmaxf(rm[0][t], rm[1][t]), fmaxf(rm[2][t], rm[3][t]));
        const long long o = ((long long)b * 8 + scn) * Dc + ct * 64 + t;
        psum[o] = s;
        pmax[o] = m;
    }
}

__global__ __launch_bounds__(256) void pool_red_kernel(const float* __restrict__ psum,
                                                       const float* __restrict__ pmax,
                                                       float* __restrict__ gpool)
{
    const int idx = blockIdx.x * 256 + threadIdx.x;
    const int b = idx / Dc, c = idx % Dc;
    float s = 0.f, m = -INFINITY;
#pragma unroll
    for (int i = 0; i < 8; ++i) {
        const long long o = ((long long)b * 8 + i) * Dc + c;
        s += psum[o];
        m = fmaxf(m, pmax[o]);
    }
    gpool[(long long)b * 1536 + c] = s * (1.f / Sc);
    gpool[(long long)b * 1536 + Dc + c] = m;
}

// ---------------- skinny GEMM: out[16][768] = in[16][K] @ W[K][768] ----------------
__global__ __launch_bounds__(256) void skinny_partial(const float* __restrict__ in,
                                                      const float* __restrict__ W,
                                                      float* __restrict__ part, int K)
{
    __shared__ float sin_[16][96];
    const int t = threadIdx.x;
    const int nt = blockIdx.x, kc = blockIdx.y;
    const int k0 = kc * 96;
    for (int idx = t; idx < 16 * 96; idx += 256) {
        const int b = idx / 96, c = idx % 96;
        sin_[b][c] = in[(long long)b * K + k0 + c];
    }
    __syncthreads();
    const int n = nt * 64 + (t & 63), kg = t >> 6;
    float acc[16];
#pragma unroll
    for (int b = 0; b < 16; ++b) acc[b] = 0.f;
    for (int kk = 0; kk < 24; ++kk) {
        const float wv = W[(long long)(k0 + kg * 24 + kk) * Dc + n];
#pragma unroll
        for (int b = 0; b < 16; ++b) acc[b] += sin_[b][kg * 24 + kk] * wv;
    }
    float* dst = part + ((long long)(kc * 4 + kg) * 16) * Dc + n;
#pragma unroll
    for (int b = 0; b < 16; ++b) dst[(long long)b * Dc] = acc[b];
}

__global__ __launch_bounds__(256) void skinny_reduce(const float* __restrict__ part,
                                                     const float* __restrict__ bias,
                                                     float* __restrict__ outp,
                                                     int nslices, int do_sigmoid)
{
    const int idx = blockIdx.x * 256 + threadIdx.x;
    const int n = idx % Dc;
    float s = bias[n];
    for (int i = 0; i < nslices; ++i) s += part[(long long)i * (16 * Dc) + idx];
    if (do_sigmoid) s = 1.f / (1.f + __expf(-s));
    outp[idx] = s;
}

__global__ __launch_bounds__(256) void final_kernel(const float* __restrict__ x,
                                                    const float* __restrict__ gate,
                                                    const float* __restrict__ gc,
                                                    float* __restrict__ outp)
{
    const long long idx = (long long)blockIdx.x * 256 + threadIdx.x;
    const int c = (int)(idx % Dc);
    const long long bs = idx / Dc;
    const int b = (int)(bs / Sc);
    outp[idx] = x[idx] + gate[b * Dc + c] * gc[b * Dc + c];
}

// ---------------- launch ----------------
extern "C" void kernel_launch(void* const* d_in, const int* in_sizes, int n_in,
                              void* d_out, int out_size, void* d_ws, size_t ws_size,
                              hipStream_t stream)
{
    (void)in_sizes; (void)n_in; (void)out_size; (void)ws_size;

    const float* X       = (const float*)d_in[0];
    const int*   tok     = (const int*)d_in[1];
    const float* Wq      = (const float*)d_in[3];
    const float* bq      = (const float*)d_in[4];
    const float* Wk      = (const float*)d_in[5];
    const float* bk      = (const float*)d_in[6];
    const float* rel_emb = (const float*)d_in[7];
    const float* W0      = (const float*)d_in[8];
    const float* b0      = (const float*)d_in[9];
    const float* W1      = (const float*)d_in[10];
    const float* b1      = (const float*)d_in[11];
    const float* scale_w = (const float*)d_in[12];
    const float* Wf      = (const float*)d_in[13];
    const float* bf      = (const float*)d_in[14];
    const float* Wfc     = (const float*)d_in[15];
    const float* bfc     = (const float*)d_in[16];
    const float* Wg      = (const float*)d_in[17];
    const float* bg      = (const float*)d_in[18];

    float* outp = (float*)d_out;
    const long long NBSD = (long long)Bc * Sc * Dc;   // 6291456
    float* adj = outp + NBSD;

    char* wsb = (char*)d_ws;
    const long long MiB = 1048576LL;
    // R0 [0,12MiB): Xbf (phase 1) -> {rb_bf, qmbf, relbf} (phase 1b) -> smalls (phase 3)
    unsigned short* Xbf   = (unsigned short*)(wsb);
    unsigned short* rb_bf = (unsigned short*)(wsb);                 // 6 MiB
    unsigned short* qmbf  = (unsigned short*)(wsb + 6 * MiB);       // 1.5 MiB
    unsigned short* relbf = (unsigned short*)(wsb + 8 * MiB);       // 72 KiB
    float* gpool   = (float*)(wsb);
    float* gcb     = (float*)(wsb + 128 * 1024);
    float* gate    = (float*)(wsb + 192 * 1024);
    float* poolsum = (float*)(wsb + 256 * 1024);
    float* poolmax = (float*)(wsb + 640 * 1024);
    float* pp1     = (float*)(wsb + 1 * MiB);   // 3 MiB
    float* pp2     = (float*)(wsb + 4 * MiB);   // 1.5 MiB
    // R1 [12,24): Qfl -> combbf
    unsigned short* Qfl    = (unsigned short*)(wsb + 12 * MiB);
    unsigned short* combbf = Qfl;
    // R2 [24,36): Kfl -> out1bf
    unsigned short* Kfl    = (unsigned short*)(wsb + 24 * MiB);
    unsigned short* out1bf = Kfl;
    // R3 [36,48): Xt -> out1t ; xf32 spans [36,60)
    unsigned short* Xt    = (unsigned short*)(wsb + 36 * MiB);
    unsigned short* out1t = Xt;
    float*          xf    = (float*)(wsb + 36 * MiB);
    // R4 [48,56): adjbf
    unsigned short* adjbf = (unsigned short*)(wsb + 48 * MiB);
    // R5 [56,68): Wqt/Wkt (early; contiguous => merged [1536][768]) -> axbf
    unsigned short* Wqt  = (unsigned short*)(wsb + 56 * MiB);
    unsigned short* Wkt  = (unsigned short*)(wsb + 56 * MiB + 1179648);
    unsigned short* axbf = (unsigned short*)(wsb + 56 * MiB);
    // WT [68MiB..): persistent weights + denom + bqk
    unsigned short* W0t = (unsigned short*)(wsb + 68 * MiB);
    unsigned short* W1t = (unsigned short*)(wsb + 68 * MiB + 1179648);
    unsigned short* Wft = (unsigned short*)(wsb + 68 * MiB + 2359296);
    float*          denom = (float*)(wsb + 68 * MiB + 3538944);
    float*          bqk   = (float*)(wsb + 68 * MiB + 3538944 + 32768);

    const float qscale = 0.10206207261596577f;  // 1/sqrt(96)

    auto gemm = [&](const unsigned short* A, const unsigned short* Bt, int M, int N, int K,
                    int ldc, long long sA, long long sB, long long sC, int batch,
                    const float* bias, const float* den, int relu,
                    float* Cf, unsigned short* Cbf, float bscale,
                    const unsigned short* comb_o1, const float* sw,
                    int qk_mode, unsigned short* Kfl_out) {
        dim3 grid(N / 64, M / 128, batch);
        gemm_bf16<<<grid, 256, 0, stream>>>(A, Bt, K, ldc, sA, sB, sC, bias, den, relu,
                                            Cf, Cbf, bscale, comb_o1, sw, qk_mode, Kfl_out);
    };

    // a: X -> bf16
    cvt_bf16_kernel<<<(int)(NBSD / 2048), 256, 0, stream>>>(X, Xbf);
    // b: all 5 weight transposes + bias concat
    WT5 wt;
    wt.s[0] = Wq;  wt.d[0] = Wqt;
    wt.s[1] = Wk;  wt.d[1] = Wkt;
    wt.s[2] = W0;  wt.d[2] = W0t;
    wt.s[3] = W1;  wt.d[3] = W1t;
    wt.s[4] = Wf;  wt.d[4] = Wft;
    wtrans5_kernel<<<dim3(12, 12, 5), 256, 0, stream>>>(wt);
    catbias_kernel<<<6, 256, 0, stream>>>(bq, bk, bqk);
    // c: merged Q|K projection (N=1536) -> fragment-linear Qfl/Kfl, qscale folded into Q
    gemm(Xbf, Wqt, Bc * Sc, 2 * Dc, Dc, 0, 0, 0, 0, 1, bqk, nullptr, 0,
         nullptr, Qfl, qscale, nullptr, nullptr, 1, Kfl);
    // e: Xt (transpose while Xbf still live)
    atrans_kernel<<<dim3(12, 8, 16), 256, 0, stream>>>(Xbf, Xt);
    // f,g: qmean + rel pad (overlay Xbf region — Xbf dead now)
    qmean_kernel<<<(Bc * Sc * DKc) / 256, 256, 0, stream>>>(Qfl, qmbf);
    relpad_kernel<<<(RBLD * DKc) / 256, 256, 0, stream>>>(rel_emb, relbf);
    // h: rb = qmean @ rel^T (M=8192, N=384, K=96), bf16 row-major out
    gemm(qmbf, relbf, Bc * Sc, RBLD, DKc, RBLD, 0, 0, 0, 1, nullptr, nullptr, 0,
         nullptr, rb_bf, 1.f, nullptr, nullptr, 0, nullptr);
    // i: fused adjacency
    adj_mfma_kernel<<<Bc * (Sc / 16), 256, 0, stream>>>(Qfl, Kfl, tok, rb_bf, adj, adjbf, denom);
    // j: ax = adj @ X (batched; B = Xt)
    gemm(adjbf, Xt, Sc, Dc, Sc, Dc, (long long)Sc * Sc, (long long)Dc * Sc, (long long)Sc * Dc,
         Bc, nullptr, nullptr, 0, nullptr, axbf, 1.f, nullptr, nullptr, 0, nullptr);
    // k: out1 = relu((ax @ W0 + b0)/denom)
    gemm(axbf, W0t, Bc * Sc, Dc, Dc, Dc, 0, 0, 0, 1, b0, denom, 1,
         nullptr, out1bf, 1.f, nullptr, nullptr, 0, nullptr);
    // l: out1t
    atrans_kernel<<<dim3(12, 8, 16), 256, 0, stream>>>(out1bf, out1t);
    // m: ax2 = adj @ out1 (batched)
    gemm(adjbf, out1t, Sc, Dc, Sc, Dc, (long long)Sc * Sc, (long long)Dc * Sc, (long long)Sc * Dc,
         Bc, nullptr, nullptr, 0, nullptr, axbf, 1.f, nullptr, nullptr, 0, nullptr);
    // n: combined = w0*out1 + w1*relu((ax2 @ W1 + b1)/denom)  (comb fused)
    gemm(axbf, W1t, Bc * Sc, Dc, Dc, Dc, 0, 0, 0, 1, b1, denom, 1,
         nullptr, combbf, 1.f, out1bf, scale_w, 0, nullptr);
    // o: x = combined @ Wf + bf (f32)
    gemm(combbf, Wft, Bc * Sc, Dc, Dc, Dc, 0, 0, 0, 1, bf, nullptr, 0,
         xf, nullptr, 1.f, nullptr, nullptr, 0, nullptr);
    // p: pooling
    pool_part_kernel<<<dim3(12, 8, 16), 256, 0, stream>>>(xf, poolsum, poolmax);
    pool_red_kernel<<<(Bc * Dc) / 256, 256, 0, stream>>>(poolsum, poolmax, gpool);
    // q: gc = [gavg|gmax] @ Wfc + bfc ; gate = sigmoid(gc @ Wg + bg)
    skinny_partial<<<dim3(12, 16), 256, 0, stream>>>(gpool, Wfc, pp1, 2 * Dc);
    skinny_reduce<<<(Bc * Dc) / 256, 256, 0, stream>>>(pp1, bfc, gcb, 64, 0);
    skinny_partial<<<dim3(12, 8), 256, 0, stream>>>(gcb, Wg, pp2, Dc);
    skinny_reduce<<<(Bc * Dc) / 256, 256, 0, stream>>>(pp2, bg, gate, 32, 1);
    // r: outputs = x + gate*gc
    final_kernel<<<(int)(NBSD / 256), 256, 0, stream>>>(xf, gate, gcb, outp);
}